// Round 10
// baseline (678.445 us; speedup 1.0000x reference)
//
#include <hip/hip_runtime.h>
#include <hip/hip_bf16.h>

#define HID 128

typedef unsigned int uint;
typedef unsigned short ushort;
typedef short short8 __attribute__((ext_vector_type(8)));
typedef float f32x4 __attribute__((ext_vector_type(4)));

static inline int cdiv_i(long a, long b) { return (int)((a + b - 1) / b); }

__device__ __forceinline__ float bf2f(uint hi) {
    return __builtin_bit_cast(float, hi << 16);
}
__device__ __forceinline__ ushort f2bf(float f) {  // RNE
    uint u = __builtin_bit_cast(uint, f);
    u = (u + 0x7fffu + ((u >> 16) & 1u)) >> 16;
    return (ushort)u;
}

// ---------------------------------------------------------------------------
// Weight folding: Pout rows 0..127 = W1@W2@W3, row 128 = b1@W2@W3,
// row 129 = b2@W3 (augmented fp32 matmuls).
// ---------------------------------------------------------------------------
__global__ void build_aug(const float* __restrict__ W1, const float* __restrict__ b1,
                          const float* __restrict__ b2,
                          float* __restrict__ aug1, float* __restrict__ aug2) {
    const int i = blockIdx.x * 256 + threadIdx.x;
    if (i < 128 * 128) aug1[i] = W1[i];
    else if (i < 129 * 128) aug1[i] = b1[i - 128 * 128];
    if (i < 128) aug2[129 * 128 + i] = b2[i];
}

__global__ void matmul128f(const float* __restrict__ A, const float* __restrict__ B,
                           float* __restrict__ C, int M) {
    const int idx = blockIdx.x * 256 + threadIdx.x;
    if (idx >= M * 128) return;
    const int i = idx >> 7, j = idx & 127;
    float s = 0.f;
#pragma unroll 8
    for (int k = 0; k < 128; ++k) s += A[i * 128 + k] * B[k * 128 + j];
    C[idx] = s;
}

// ---------------------------------------------------------------------------
// Weight pre-transpose: Wt[m][n][k] = bf16(W[m][k][n]), 4 matrices.
// ---------------------------------------------------------------------------
struct W4 { const float* w[4]; };

__global__ void wtrans_k(W4 ws, ushort* __restrict__ out) {
    const int idx = blockIdx.x * 256 + threadIdx.x;
    if (idx >= 4 * 16384) return;
    const int m = idx >> 14;
    const int e = idx & 16383;
    const int n = e >> 7, k = e & 127;
    out[idx] = f2bf(ws.w[m][k * 128 + n]);
}

// ---------------------------------------------------------------------------
// MFMA GEMM machinery. Wt (bf16, [n][k]) staged to LDS stride 136, uint4 copy.
// ---------------------------------------------------------------------------
__device__ __forceinline__ void stage_wt(const ushort* __restrict__ Wt,
                                         ushort* __restrict__ wl) {
    const int t = threadIdx.x;
    const int row = t >> 1, half = (t & 1) * 64;
    const uint4* src = (const uint4*)(Wt + row * 128 + half);
    uint4* dst = (uint4*)(wl + row * 136 + half);
#pragma unroll
    for (int i = 0; i < 8; ++i) dst[i] = src[i];
}

template <typename AT>
__device__ __forceinline__ void load_afrag(const AT* __restrict__ A, long row,
                                           int koff, short8& af) {
    if constexpr (__is_same(AT, ushort)) {
        const uint4 raw = *(const uint4*)(A + row * 128 + koff);
        af = __builtin_bit_cast(short8, raw);
    } else {
        const float4* p = (const float4*)(A + row * 128 + koff);
        const float4 x0 = p[0], x1 = p[1];
        af[0] = (short)f2bf(x0.x); af[1] = (short)f2bf(x0.y);
        af[2] = (short)f2bf(x0.z); af[3] = (short)f2bf(x0.w);
        af[4] = (short)f2bf(x1.x); af[5] = (short)f2bf(x1.y);
        af[6] = (short)f2bf(x1.z); af[7] = (short)f2bf(x1.w);
    }
}

template <typename AT, typename OT>
__device__ __forceinline__ void mfma_tile(const AT* __restrict__ A,
                                          const ushort* __restrict__ wl,
                                          const float* __restrict__ bias,
                                          OT* __restrict__ C,
                                          long m0blk, long rowEnd) {
    const int tid = threadIdx.x;
    const int wave = tid >> 6, lane = tid & 63;
    const int r = lane & 15, q = lane >> 4;
    const long m0 = m0blk + wave * 32;

    f32x4 acc[2][8];
#pragma unroll
    for (int mi = 0; mi < 2; ++mi)
#pragma unroll
        for (int ni = 0; ni < 8; ++ni) acc[mi][ni] = (f32x4)0.f;

#pragma unroll
    for (int t = 0; t < 4; ++t) {
        const int koff = t * 32 + q * 8;
        short8 bfr[8];
#pragma unroll
        for (int ni = 0; ni < 8; ++ni) {
            const uint4 raw = *(const uint4*)(&wl[(ni * 16 + r) * 136 + koff]);
            bfr[ni] = __builtin_bit_cast(short8, raw);
        }
#pragma unroll
        for (int mi = 0; mi < 2; ++mi) {
            long row = m0 + mi * 16 + r;
            if (row >= rowEnd) row = rowEnd - 1;
            short8 af;
            load_afrag<AT>(A, row, koff, af);
#pragma unroll
            for (int ni = 0; ni < 8; ++ni)
                acc[mi][ni] = __builtin_amdgcn_mfma_f32_16x16x32_bf16(
                    af, bfr[ni], acc[mi][ni], 0, 0, 0);
        }
    }

#pragma unroll
    for (int mi = 0; mi < 2; ++mi) {
#pragma unroll
        for (int ni = 0; ni < 8; ++ni) {
            const int col = ni * 16 + r;
            const float bv = bias ? bias[col] : 0.f;
#pragma unroll
            for (int reg = 0; reg < 4; ++reg) {
                const long row = m0 + mi * 16 + q * 4 + reg;
                if (row < rowEnd) {
                    const float v = acc[mi][ni][reg] + bv;
                    if constexpr (__is_same(OT, ushort))
                        C[row * 128 + col] = f2bf(v);
                    else
                        C[row * 128 + col] = v;
                }
            }
        }
    }
}

template <typename OT>
__global__ __launch_bounds__(256) void gemm_gcn(const ushort* __restrict__ A,
                                                const ushort* __restrict__ Wt,
                                                const float* __restrict__ bias,
                                                OT* __restrict__ C, int M) {
    __shared__ ushort wl[128 * 136];
    stage_wt(Wt, wl);
    __syncthreads();
    const long m0 = (long)blockIdx.x * 256;
    mfma_tile<ushort, OT>(A, wl, bias, C, m0, M);
    if (m0 + 128 < M)
        mfma_tile<ushort, OT>(A, wl, bias, C, m0 + 128, M);
}

// ---------------------------------------------------------------------------
// Ontology GEMM with fused attention-score epilogue.
// ---------------------------------------------------------------------------
struct GOnto {
    const ushort* Wt0; const ushort* Wt1; const ushort* Wt2;
    const float* s0; const float* s1; const float* s2;
    const float* d0; const float* d1; const float* d2;
    int bs1, bs2;
    int r1, r2, r3;
};

template <typename AT>
__global__ __launch_bounds__(256) void gemm_onto(const AT* x0, const AT* x1,
                                                 const AT* x2, GOnto g,
                                                 ushort* __restrict__ H,
                                                 float* __restrict__ as_o,
                                                 float* __restrict__ ad_o) {
    __shared__ ushort wl[128 * 136];
    const int b = blockIdx.x;
    const int gid = (b >= g.bs1) + (b >= g.bs2);
    const ushort* Wt = (gid == 0) ? g.Wt0 : (gid == 1) ? g.Wt1 : g.Wt2;
    const float* avs = (gid == 0) ? g.s0 : (gid == 1) ? g.s1 : g.s2;
    const float* avd = (gid == 0) ? g.d0 : (gid == 1) ? g.d1 : g.d2;
    const AT* Ag = (gid == 0) ? x0 : (gid == 1) ? x1 : x2;
    const int bloc = b - ((gid == 0) ? 0 : (gid == 1) ? g.bs1 : g.bs2);
    const long rb = (gid == 0) ? 0 : (gid == 1) ? g.r1 : g.r2;
    const long Mg = ((gid == 0) ? g.r1 : (gid == 1) ? g.r2 : g.r3) - rb;
    stage_wt(Wt, wl);
    __syncthreads();

    const int tid = threadIdx.x;
    const int wave = tid >> 6, lane = tid & 63;
    const int r = lane & 15, q = lane >> 4;
    const long m0 = (long)bloc * 128 + wave * 32;

    f32x4 acc[2][8];
#pragma unroll
    for (int mi = 0; mi < 2; ++mi)
#pragma unroll
        for (int ni = 0; ni < 8; ++ni) acc[mi][ni] = (f32x4)0.f;

#pragma unroll
    for (int t = 0; t < 4; ++t) {
        const int koff = t * 32 + q * 8;
        short8 bfr[8];
#pragma unroll
        for (int ni = 0; ni < 8; ++ni) {
            const uint4 raw = *(const uint4*)(&wl[(ni * 16 + r) * 136 + koff]);
            bfr[ni] = __builtin_bit_cast(short8, raw);
        }
#pragma unroll
        for (int mi = 0; mi < 2; ++mi) {
            long row = m0 + mi * 16 + r;
            if (row >= Mg) row = Mg - 1;
            short8 af;
            load_afrag<AT>(Ag, row, koff, af);
#pragma unroll
            for (int ni = 0; ni < 8; ++ni)
                acc[mi][ni] = __builtin_amdgcn_mfma_f32_16x16x32_bf16(
                    af, bfr[ni], acc[mi][ni], 0, 0, 0);
        }
    }

    ushort* Hg = H + rb * 128;
#pragma unroll
    for (int mi = 0; mi < 2; ++mi) {
#pragma unroll
        for (int ni = 0; ni < 8; ++ni) {
            const int col = ni * 16 + r;
#pragma unroll
            for (int reg = 0; reg < 4; ++reg) {
                const long row = m0 + mi * 16 + q * 4 + reg;
                if (row < Mg) Hg[row * 128 + col] = f2bf(acc[mi][ni][reg]);
            }
        }
    }

    float asv[8], adv[8];
#pragma unroll
    for (int ni = 0; ni < 8; ++ni) {
        asv[ni] = avs[ni * 16 + r];
        adv[ni] = avd[ni * 16 + r];
    }
#pragma unroll
    for (int mi = 0; mi < 2; ++mi) {
#pragma unroll
        for (int reg = 0; reg < 4; ++reg) {
            float ps = 0.f, pd = 0.f;
#pragma unroll
            for (int ni = 0; ni < 8; ++ni) {
                ps += acc[mi][ni][reg] * asv[ni];
                pd += acc[mi][ni][reg] * adv[ni];
            }
#pragma unroll
            for (int o = 1; o < 16; o <<= 1) {
                ps += __shfl_xor(ps, o);
                pd += __shfl_xor(pd, o);
            }
            const long row = m0 + mi * 16 + q * 4 + reg;
            if (r == 0 && row < Mg) {
                as_o[rb + row] = ps;
                ad_o[rb + row] = pd;
            }
        }
    }
}

// ---------------------------------------------------------------------------
// GAT aggregation: quarter-wave per node.
// ---------------------------------------------------------------------------
struct GatP {
    int r1, r2;
    int ob0, ob1, ob2;
    const float* b0; const float* b1; const float* b2;
};

__device__ __forceinline__ void acc8(float* acc, float w, const uint4 v) {
    acc[0] += w * bf2f(v.x & 0xffff);
    acc[1] += w * bf2f(v.x >> 16);
    acc[2] += w * bf2f(v.y & 0xffff);
    acc[3] += w * bf2f(v.y >> 16);
    acc[4] += w * bf2f(v.z & 0xffff);
    acc[5] += w * bf2f(v.z >> 16);
    acc[6] += w * bf2f(v.w & 0xffff);
    acc[7] += w * bf2f(v.w >> 16);
}

__global__ __launch_bounds__(256) void gat_all(const ushort* __restrict__ h,
                                               const float* __restrict__ as,
                                               const float* __restrict__ ad,
                                               const int* __restrict__ offs,
                                               const int* __restrict__ srcl,
                                               GatP p, ushort* __restrict__ out,
                                               int Mtot) {
    const int node = blockIdx.x * 16 + (threadIdx.x >> 4);
    const int ql = threadIdx.x & 15;
    if (node >= Mtot) return;
    const int gid = (node >= p.r1) + (node >= p.r2);
    const int rb = (gid == 0) ? 0 : (gid == 1) ? p.r1 : p.r2;
    const int ob = (gid == 0) ? p.ob0 : (gid == 1) ? p.ob1 : p.ob2;
    const float* bias = (gid == 0) ? p.b0 : (gid == 1) ? p.b1 : p.b2;
    const int local = node - rb;
    const int beg = offs[ob + local], end = offs[ob + local + 1];
    const float adv = ad[node];
    float m = -1e30f;
    for (int j = beg; j < end; ++j) {
        float e = as[rb + srcl[j]] + adv;
        e = (e > 0.f) ? e : 0.2f * e;
        m = fmaxf(m, e);
    }
    float denom = 0.f;
    float acc[8] = {0.f, 0.f, 0.f, 0.f, 0.f, 0.f, 0.f, 0.f};
    int j = beg;
    for (; j + 2 <= end; j += 2) {
        const int s0 = srcl[j], s1 = srcl[j + 1];
        float e0 = as[rb + s0] + adv; e0 = (e0 > 0.f) ? e0 : 0.2f * e0;
        float e1 = as[rb + s1] + adv; e1 = (e1 > 0.f) ? e1 : 0.2f * e1;
        const float w0 = __expf(e0 - m), w1 = __expf(e1 - m);
        const uint4 v0 = *(const uint4*)(h + (size_t)(rb + s0) * 128 + ql * 8);
        const uint4 v1 = *(const uint4*)(h + (size_t)(rb + s1) * 128 + ql * 8);
        denom += w0 + w1;
        acc8(acc, w0, v0);
        acc8(acc, w1, v1);
    }
    if (j < end) {
        const int s0 = srcl[j];
        float e0 = as[rb + s0] + adv; e0 = (e0 > 0.f) ? e0 : 0.2f * e0;
        const float w0 = __expf(e0 - m);
        const uint4 v0 = *(const uint4*)(h + (size_t)(rb + s0) * 128 + ql * 8);
        denom += w0;
        acc8(acc, w0, v0);
    }
    const float inv = 1.f / denom;
    const float4 bv0 = *(const float4*)(bias + ql * 8);
    const float4 bv1 = *(const float4*)(bias + ql * 8 + 4);
    uint4 o;
    o.x = (uint)f2bf(acc[0] * inv + bv0.x) | ((uint)f2bf(acc[1] * inv + bv0.y) << 16);
    o.y = (uint)f2bf(acc[2] * inv + bv0.z) | ((uint)f2bf(acc[3] * inv + bv0.w) << 16);
    o.z = (uint)f2bf(acc[4] * inv + bv1.x) | ((uint)f2bf(acc[5] * inv + bv1.y) << 16);
    o.w = (uint)f2bf(acc[6] * inv + bv1.z) | ((uint)f2bf(acc[7] * inv + bv1.w) << 16);
    *(uint4*)(out + (size_t)node * 128 + ql * 8) = o;
}

// ---------------------------------------------------------------------------
// Batched CSR build (8 lists; self-loops atomic-free in reserved last slot).
// Patient slots -> int4 record {src, gxi, nw_bits, 0}, written ONLY for dst
// nodes whose edge lists will actually be read (mk != 0).
// ---------------------------------------------------------------------------
struct CsrDesc {
    const int* esrc[8];
    const int* edst[8];
    int ebase[9];
    int nbase[9];
    int totE;
};

__global__ void csr_count_b(CsrDesc d, int* __restrict__ cnt, int* __restrict__ pos) {
    const int i = blockIdx.x * 256 + threadIdx.x;
    if (i >= d.totE) return;
    int li = 0;
#pragma unroll
    for (int k = 1; k < 8; ++k) li += (i >= d.ebase[k]);
    const int v = d.nbase[li] + d.edst[li][i - d.ebase[li]];
    pos[i] = atomicAdd(&cnt[v], 1);
}

__global__ void csr_fill_b(CsrDesc d, const int* __restrict__ offs,
                           const int* __restrict__ pos, const int* __restrict__ cnt,
                           int* __restrict__ srcl, int4* __restrict__ pedge,
                           const float* __restrict__ dinv,
                           const int* __restrict__ lx, const int* __restrict__ rx,
                           const int* __restrict__ mk,
                           int NP, int NV, int pB) {
    const int i = blockIdx.x * 256 + threadIdx.x;
    int v, s, li, idx;
    if (i < d.totE) {
        li = 0;
#pragma unroll
        for (int k = 1; k < 8; ++k) li += (i >= d.ebase[k]);
        const int j = i - d.ebase[li];
        v = d.nbase[li] + d.edst[li][j];
        s = d.esrc[li][j];
        idx = offs[v] + pos[i];
    } else if (i < d.totE + NV) {
        v = i - d.totE;
        li = 0;
#pragma unroll
        for (int k = 1; k < 8; ++k) li += (v >= d.nbase[k]);
        s = v - d.nbase[li];
        idx = offs[v] + cnt[v];
    } else return;
    if (li >= 6) {
        const int n2l = v - d.nbase[6];
        if (mk[n2l] == 0) return;   // edge list never read
        const int sg = (li - 6) * NP + s;
        int4 rec;
        rec.x = sg;
        rec.y = (li == 7 ? rx : lx)[s];
        rec.z = __float_as_int(dinv[n2l] * dinv[sg]);
        rec.w = 0;
        pedge[idx - pB] = rec;
    } else {
        srcl[idx] = s;
    }
}

// First node of each graph (sorted batch); sets fin bit (1) in mk.
__global__ void first_node(const int* __restrict__ bL, const int* __restrict__ bR,
                           int NP, int* __restrict__ gfL, int* __restrict__ gfR,
                           int* __restrict__ mk) {
    const int i = blockIdx.x * 256 + threadIdx.x;
    if (i >= 2 * NP) return;
    const int side = i >= NP;
    const int ii = i - (side ? NP : 0);
    const int* b = side ? bR : bL;
    int* gf = side ? gfR : gfL;
    const int cur = b[ii];
    const int prev = (ii == 0) ? -1 : b[ii - 1];
    if (cur > prev) {
        for (int g = prev + 1; g <= cur; ++g) gf[g] = ii;
        mk[i] = 1;
    }
}

// ---------------------------------------------------------------------------
// Backward reachability marking over raw patient edge lists.
// mk bits: 1 = final node, 2 = needed in t2 (list2), 4 = needed in t1 (list1).
// ---------------------------------------------------------------------------
__device__ __forceinline__ void try_append(int* __restrict__ mk, int bit, int n,
                                           int* __restrict__ list, int* __restrict__ cnt) {
    if ((atomicOr(&mk[n], bit) & bit) == 0)
        list[atomicAdd(cnt, 1)] = n;
}

__global__ void mark_k(const int* __restrict__ lEg, const int* __restrict__ rEg,
                       int EP, int NP, int* __restrict__ mk, int testBit, int setBit,
                       int* __restrict__ list, int* __restrict__ cnt) {
    const int i = blockIdx.x * 256 + threadIdx.x;
    int src, dst;
    if (i < 2 * EP) {
        const int side = i >= EP;
        const int e = i - side * EP;
        const int* eg = side ? rEg : lEg;
        src = side * NP + eg[e];
        dst = side * NP + eg[EP + e];
    } else if (i < 2 * EP + 2 * NP) {
        src = dst = i - 2 * EP;   // self-loop
    } else return;
    if (mk[dst] & testBit) try_append(mk, setBit, src, list, cnt);
}

// ---------------------------------------------------------------------------
// 3-phase exclusive scan over (cnt[v]+1); emits dinv for the patient range.
// ---------------------------------------------------------------------------
__global__ __launch_bounds__(1024) void scan_tile(const int* __restrict__ in,
                                                  int* __restrict__ out,
                                                  int* __restrict__ bsum, int n,
                                                  int pn0, int pcnt,
                                                  float* __restrict__ dinv) {
    __shared__ int buf[1024];
    const int tid = threadIdx.x;
    const int i = blockIdx.x * 1024 + tid;
    const int v = (i < n) ? (in[i] + 1) : 0;
    if (i >= pn0 && i < pn0 + pcnt)
        dinv[i - pn0] = rsqrtf(fmaxf((float)v, 1e-12f));
    buf[tid] = v;
    __syncthreads();
    int x = v;
    for (int o = 1; o < 1024; o <<= 1) {
        const int t = (tid >= o) ? buf[tid - o] : 0;
        __syncthreads();
        x += t;
        buf[tid] = x;
        __syncthreads();
    }
    if (i < n) out[i] = x - v;
    if (tid == 1023) bsum[blockIdx.x] = x;
}

__global__ __launch_bounds__(1024) void scan_single(int* __restrict__ bsum, int nb) {
    __shared__ int buf[1024];
    const int tid = threadIdx.x;
    const int v = (tid < nb) ? bsum[tid] : 0;
    buf[tid] = v;
    __syncthreads();
    int x = v;
    for (int o = 1; o < 1024; o <<= 1) {
        const int t = (tid >= o) ? buf[tid - o] : 0;
        __syncthreads();
        x += t;
        buf[tid] = x;
        __syncthreads();
    }
    if (tid < nb) bsum[tid] = x - v;
    if (tid == 1023) bsum[nb] = x;
}

__global__ void scan_add(int* __restrict__ out, const int* __restrict__ bsum,
                         int n, int nb) {
    const int i = blockIdx.x * 256 + threadIdx.x;
    if (i < n) out[i] += bsum[i >> 10];
    else if (i == n) out[i] = bsum[nb];
}

// ---------------------------------------------------------------------------
// allemb (bf16): row 0 = spec (fp32 src), then 3 ontology maps from bf16 oE.
// ---------------------------------------------------------------------------
struct EmbD {
    const float* spec; const ushort* oE;
    const int* m0; const int* m1; const int* m2;
    int lb2, lb3;
    int r1, r2;
    long ALLr;
};

__global__ void build_emb(EmbD d, ushort* __restrict__ out) {
    const long t = (long)blockIdx.x * 256 + threadIdx.x;
    if (t >= d.ALLr * 16) return;
    const int row = (int)(t >> 4), c = (int)(t & 15);
    uint4 o;
    if (row == 0) {
        const float4 f0 = ((const float4*)d.spec)[c * 2];
        const float4 f1 = ((const float4*)d.spec)[c * 2 + 1];
        o.x = (uint)f2bf(f0.x) | ((uint)f2bf(f0.y) << 16);
        o.y = (uint)f2bf(f0.z) | ((uint)f2bf(f0.w) << 16);
        o.z = (uint)f2bf(f1.x) | ((uint)f2bf(f1.y) << 16);
        o.w = (uint)f2bf(f1.z) | ((uint)f2bf(f1.w) << 16);
    } else {
        const int seg = (row >= d.lb2) + (row >= d.lb3);
        const int local = row - ((seg == 0) ? 1 : (seg == 1) ? d.lb2 : d.lb3);
        const int* mp = (seg == 0) ? d.m0 : (seg == 1) ? d.m1 : d.m2;
        const int rb = (seg == 0) ? 0 : (seg == 1) ? d.r1 : d.r2;
        o = ((const uint4*)(d.oE + (size_t)(rb + mp[local]) * 128))[c];
    }
    ((uint4*)out)[(size_t)row * 16 + c] = o;
}

// ---------------------------------------------------------------------------
// GCN aggregations over compact node lists; edge record = int4 {src,gxi,nw,0}.
// ---------------------------------------------------------------------------
__global__ __launch_bounds__(256) void gcn_agg1(const ushort* __restrict__ A3,
                                                const int4* __restrict__ pedge,
                                                const int* __restrict__ offs6,
                                                const float* __restrict__ c1,
                                                ushort* __restrict__ t1,
                                                const int* __restrict__ list1,
                                                const int* __restrict__ cnt1, int pB) {
    const int id = blockIdx.x * 16 + (threadIdx.x >> 4);
    const int ql = threadIdx.x & 15;
    if (id >= *cnt1) return;
    const int n2 = list1[id];
    const int beg = offs6[n2] - pB, end = offs6[n2 + 1] - pB;
    float acc[8] = {0.f, 0.f, 0.f, 0.f, 0.f, 0.f, 0.f, 0.f};
    int j = beg;
    for (; j + 2 <= end; j += 2) {
        const int4 r0 = pedge[j], r1 = pedge[j + 1];
        const float w0 = __int_as_float(r0.z), w1 = __int_as_float(r1.z);
        const uint4 v0 = *(const uint4*)(A3 + (size_t)r0.y * 128 + ql * 8);
        const uint4 v1 = *(const uint4*)(A3 + (size_t)r1.y * 128 + ql * 8);
        acc8(acc, w0, v0);
        acc8(acc, w1, v1);
    }
    if (j < end) {
        const int4 r0 = pedge[j];
        const uint4 v0 = *(const uint4*)(A3 + (size_t)r0.y * 128 + ql * 8);
        acc8(acc, __int_as_float(r0.z), v0);
    }
    const float4 bv0 = *(const float4*)(c1 + ql * 8);
    const float4 bv1 = *(const float4*)(c1 + ql * 8 + 4);
    uint4 o;
    o.x = (uint)f2bf(acc[0] + bv0.x) | ((uint)f2bf(acc[1] + bv0.y) << 16);
    o.y = (uint)f2bf(acc[2] + bv0.z) | ((uint)f2bf(acc[3] + bv0.w) << 16);
    o.z = (uint)f2bf(acc[4] + bv1.x) | ((uint)f2bf(acc[5] + bv1.y) << 16);
    o.w = (uint)f2bf(acc[6] + bv1.z) | ((uint)f2bf(acc[7] + bv1.w) << 16);
    *(uint4*)(t1 + (size_t)n2 * 128 + ql * 8) = o;
}

__device__ __forceinline__ void gcn_q_acc(const ushort* __restrict__ x,
                                          const int4* __restrict__ pedge,
                                          int beg, int end, int ql, float* acc) {
    int j = beg;
    for (; j + 2 <= end; j += 2) {
        const int4 r0 = pedge[j], r1 = pedge[j + 1];
        const float w0 = __int_as_float(r0.z), w1 = __int_as_float(r1.z);
        const uint4 v0 = *(const uint4*)(x + (size_t)r0.x * 128 + ql * 8);
        const uint4 v1 = *(const uint4*)(x + (size_t)r1.x * 128 + ql * 8);
        acc8(acc, w0, v0);
        acc8(acc, w1, v1);
    }
    if (j < end) {
        const int4 r0 = pedge[j];
        const uint4 v0 = *(const uint4*)(x + (size_t)r0.x * 128 + ql * 8);
        acc8(acc, __int_as_float(r0.z), v0);
    }
}

__global__ __launch_bounds__(256) void gcn_agg2(const ushort* __restrict__ t1,
                                                const int4* __restrict__ pedge,
                                                const int* __restrict__ offs6,
                                                const float* __restrict__ c2,
                                                ushort* __restrict__ t2,
                                                const int* __restrict__ list2,
                                                const int* __restrict__ cnt2, int pB) {
    const int id = blockIdx.x * 16 + (threadIdx.x >> 4);
    const int ql = threadIdx.x & 15;
    if (id >= *cnt2) return;
    const int n2 = list2[id];
    const int beg = offs6[n2] - pB, end = offs6[n2 + 1] - pB;
    float acc[8] = {0.f, 0.f, 0.f, 0.f, 0.f, 0.f, 0.f, 0.f};
    gcn_q_acc(t1, pedge, beg, end, ql, acc);
    const float4 bv0 = *(const float4*)(c2 + ql * 8);
    const float4 bv1 = *(const float4*)(c2 + ql * 8 + 4);
    uint4 o;
    o.x = (uint)f2bf(acc[0] + bv0.x) | ((uint)f2bf(acc[1] + bv0.y) << 16);
    o.y = (uint)f2bf(acc[2] + bv0.z) | ((uint)f2bf(acc[3] + bv0.w) << 16);
    o.z = (uint)f2bf(acc[4] + bv1.x) | ((uint)f2bf(acc[5] + bv1.y) << 16);
    o.w = (uint)f2bf(acc[6] + bv1.z) | ((uint)f2bf(acc[7] + bv1.w) << 16);
    *(uint4*)(t2 + (size_t)n2 * 128 + ql * 8) = o;
}

// Layer 3: aggregate only final nodes; +b3; fp32 output straight to lfrf.
__global__ __launch_bounds__(256) void gcn_final(const ushort* __restrict__ t2,
                                                 const int4* __restrict__ pedge,
                                                 const int* __restrict__ offs6,
                                                 const int* __restrict__ gfL,
                                                 const int* __restrict__ gfR,
                                                 const float* __restrict__ b3,
                                                 float* __restrict__ lfrf,
                                                 int B, int NP, int pB) {
    const int g2 = blockIdx.x * 16 + (threadIdx.x >> 4);
    const int ql = threadIdx.x & 15;
    if (g2 >= 2 * B) return;
    const int side = g2 >= B;
    const int gl = g2 - (side ? B : 0);
    const int n2 = (side ? NP : 0) + (side ? gfR : gfL)[gl];
    const int beg = offs6[n2] - pB, end = offs6[n2 + 1] - pB;
    float acc[8] = {0.f, 0.f, 0.f, 0.f, 0.f, 0.f, 0.f, 0.f};
    gcn_q_acc(t2, pedge, beg, end, ql, acc);
    const float4 bv0 = *(const float4*)(b3 + ql * 8);
    const float4 bv1 = *(const float4*)(b3 + ql * 8 + 4);
    float* op = lfrf + (size_t)g2 * 128 + ql * 8;
    op[0] = acc[0] + bv0.x; op[1] = acc[1] + bv0.y;
    op[2] = acc[2] + bv0.z; op[3] = acc[3] + bv0.w;
    op[4] = acc[4] + bv1.x; op[5] = acc[5] + bv1.y;
    op[6] = acc[6] + bv1.z; op[7] = acc[7] + bv1.w;
}

// ---------------------------------------------------------------------------
// Cosine similarity: lfrf holds left rows [0,B), right rows [B,2B).
// ---------------------------------------------------------------------------
__global__ __launch_bounds__(256) void cosine_k(const float* __restrict__ lfrf,
                                                float* __restrict__ out, int B) {
    const int g = blockIdx.x * 4 + (threadIdx.x >> 6);
    const int lane = threadIdx.x & 63;
    if (g >= B) return;
    const float2 a = *(const float2*)(lfrf + (size_t)g * 128 + lane * 2);
    const float2 b = *(const float2*)(lfrf + (size_t)(B + g) * 128 + lane * 2);
    float num = a.x * b.x + a.y * b.y;
    float na = a.x * a.x + a.y * a.y;
    float nb = b.x * b.x + b.y * b.y;
#pragma unroll
    for (int o = 32; o > 0; o >>= 1) {
        num += __shfl_down(num, o);
        na += __shfl_down(na, o);
        nb += __shfl_down(nb, o);
    }
    if (lane == 0)
        out[g] = num / (fmaxf(sqrtf(na), 1e-6f) * fmaxf(sqrtf(nb), 1e-6f));
}

// ---------------------------------------------------------------------------
extern "C" void kernel_launch(void* const* d_in, const int* in_sizes, int n_in,
                              void* d_out, int out_size, void* d_ws, size_t ws_size,
                              hipStream_t stream) {
    (void)n_in; (void)ws_size;
    // setup_inputs() dict order
    const float* spec = (const float*)d_in[0];
    const float* tabs[3] = {(const float*)d_in[1], (const float*)d_in[2], (const float*)d_in[3]};
    const float* ontW[3] = {(const float*)d_in[4], (const float*)d_in[8], (const float*)d_in[12]};
    const float* ontAs[3] = {(const float*)d_in[5], (const float*)d_in[9], (const float*)d_in[13]};
    const float* ontAd[3] = {(const float*)d_in[6], (const float*)d_in[10], (const float*)d_in[14]};
    const float* ontB[3] = {(const float*)d_in[7], (const float*)d_in[11], (const float*)d_in[15]};
    const float* gcnW[3] = {(const float*)d_in[16], (const float*)d_in[18], (const float*)d_in[20]};
    const float* gcnB[3] = {(const float*)d_in[17], (const float*)d_in[19], (const float*)d_in[21]};
    const int* e1s[3] = {(const int*)d_in[22], (const int*)d_in[24], (const int*)d_in[26]};
    const int* e2s[3] = {(const int*)d_in[23], (const int*)d_in[25], (const int*)d_in[27]};
    const int* maps[3] = {(const int*)d_in[28], (const int*)d_in[29], (const int*)d_in[30]};
    const int* left_x = (const int*)d_in[31];
    const int* right_x = (const int*)d_in[32];
    const int* left_eg = (const int*)d_in[33];
    const int* right_eg = (const int*)d_in[34];
    const int* left_batch = (const int*)d_in[35];
    const int* right_batch = (const int*)d_in[36];

    int Ms[3] = {in_sizes[1] / HID, in_sizes[2] / HID, in_sizes[3] / HID};
    int E1s[3] = {in_sizes[22] / 2, in_sizes[24] / 2, in_sizes[26] / 2};
    int E2s[3] = {in_sizes[23] / 2, in_sizes[25] / 2, in_sizes[27] / 2};
    int Ls[3] = {in_sizes[28], in_sizes[29], in_sizes[30]};
    const int NP = in_sizes[31];
    const int EP = in_sizes[33] / 2;
    const int B = out_size;
    const long ALL = 1 + (long)Ls[0] + Ls[1] + Ls[2];
    const int Mtot = Ms[0] + Ms[1] + Ms[2];
    const int r1 = Ms[0], r2 = Ms[0] + Ms[1];

    // ---- batched CSR descriptor (8 lists; self-loops implicit) ----
    CsrDesc dsc;
    int eCnt[8], nCnt[8];
    for (int i = 0; i < 3; ++i) {
        dsc.esrc[2 * i] = e1s[i];     dsc.edst[2 * i] = e1s[i] + E1s[i];
        dsc.esrc[2 * i + 1] = e2s[i]; dsc.edst[2 * i + 1] = e2s[i] + E2s[i];
        eCnt[2 * i] = E1s[i]; eCnt[2 * i + 1] = E2s[i];
        nCnt[2 * i] = Ms[i];  nCnt[2 * i + 1] = Ms[i];
    }
    dsc.esrc[6] = left_eg;  dsc.edst[6] = left_eg + EP;  eCnt[6] = EP; nCnt[6] = NP;
    dsc.esrc[7] = right_eg; dsc.edst[7] = right_eg + EP; eCnt[7] = EP; nCnt[7] = NP;
    dsc.ebase[0] = 0;
    int nb_acc = 0;
    for (int i = 0; i < 8; ++i) {
        dsc.ebase[i + 1] = dsc.ebase[i] + eCnt[i];
        dsc.nbase[i] = nb_acc;
        nb_acc += nCnt[i];
    }
    const int NV = nb_acc;
    dsc.nbase[8] = NV;
    dsc.totE = dsc.ebase[8];
    const int totEntries = dsc.totE + NV;
    const int pB = dsc.ebase[6] + dsc.nbase[6];
    const int pEntries = totEntries - pB;

    // ---- workspace layout ----
    char* ws = (char*)d_ws;
    size_t off = 0;
    auto alloc = [&](size_t bytes) -> void* {
        off = (off + 255) & ~(size_t)255;
        void* p = ws + off;
        off += bytes;
        return p;
    };
    ushort* wt4 = (ushort*)alloc((size_t)4 * 16384 * 2);   // 3 ont Wt + WpT
    float* aug1 = (float*)alloc((size_t)130 * 128 * 4);
    float* aug2 = (float*)alloc((size_t)130 * 128 * 4);
    float* Pout = (float*)alloc((size_t)130 * 128 * 4);
    ushort* allemb = (ushort*)alloc((size_t)ALL * HID * 2);
    ushort* A3 = (ushort*)alloc((size_t)ALL * HID * 2);
    float* lfrf = (float*)alloc((size_t)2 * B * HID * 4);
    int* cnt = (int*)alloc((size_t)NV * 4);
    int* offs = (int*)alloc((size_t)(NV + 1) * 4);
    int* pos = (int*)alloc((size_t)dsc.totE * 4);
    int* srcl = (int*)alloc((size_t)pB * 4);
    int4* pedge = (int4*)alloc((size_t)pEntries * 16);
    int* bsum = (int*)alloc(1025 * 4);
    float* dinv = (float*)alloc((size_t)2 * NP * 4);
    float* as = (float*)alloc((size_t)Mtot * 4);
    float* ad = (float*)alloc((size_t)Mtot * 4);
    int* gfL = (int*)alloc((size_t)(B + 1) * 4);
    int* gfR = (int*)alloc((size_t)(B + 1) * 4);
    int* mk = (int*)alloc((size_t)2 * NP * 4);
    int* list1 = (int*)alloc((size_t)2 * NP * 4);
    int* list2 = (int*)alloc((size_t)2 * NP * 4);
    int* cnt12 = (int*)alloc(2 * 4);
    ushort* t1 = (ushort*)alloc((size_t)2 * NP * HID * 2);
    // big region: ontology hbuf/obuf first, then t2
    ushort* big = (ushort*)alloc((size_t)2 * NP * HID * 2);
    ushort* hbuf = big;                              // [Mtot x 128] bf16
    ushort* obuf = big + (size_t)Mtot * HID;         // [Mtot x 128] bf16
    ushort* t2 = big;                                // [2NP x 128] bf16 (later)

    // ---- weight folding: Pout = [W1;b1;b2-aug] @ W2 @ W3 ----
    build_aug<<<cdiv_i(129 * 128, 256), 256, 0, stream>>>(gcnW[0], gcnB[0], gcnB[1],
                                                          aug1, aug2);
    matmul128f<<<cdiv_i(129 * 128, 256), 256, 0, stream>>>(aug1, gcnW[1], aug2, 129);
    matmul128f<<<cdiv_i(130 * 128, 256), 256, 0, stream>>>(aug2, gcnW[2], Pout, 130);
    const float* c1 = Pout + 128 * 128;
    const float* c2 = Pout + 129 * 128;

    // ---- weight transpose (bf16): 3 ont + folded Wp ----
    W4 w4;
    w4.w[0] = ontW[0]; w4.w[1] = ontW[1]; w4.w[2] = ontW[2]; w4.w[3] = Pout;
    wtrans_k<<<cdiv_i(4 * 16384, 256), 256, 0, stream>>>(w4, wt4);
    const ushort* wtOnt[3] = {wt4, wt4 + 16384, wt4 + 2 * 16384};
    const ushort* WpT = wt4 + 3 * 16384;

    // ---- backward reachability marks (raw edges; no CSR dependency) ----
    hipMemsetAsync(mk, 0, (size_t)2 * NP * 4, stream);
    hipMemsetAsync(cnt12, 0, 2 * 4, stream);
    first_node<<<cdiv_i(2 * NP, 256), 256, 0, stream>>>(left_batch, right_batch,
                                                        NP, gfL, gfR, mk);
    mark_k<<<cdiv_i(2 * EP + 2 * NP, 256), 256, 0, stream>>>(
        left_eg, right_eg, EP, NP, mk, 1, 2, list2, cnt12 + 1);
    mark_k<<<cdiv_i(2 * EP + 2 * NP, 256), 256, 0, stream>>>(
        left_eg, right_eg, EP, NP, mk, 2, 4, list1, cnt12 + 0);

    // ---- CSR build ----
    hipMemsetAsync(cnt, 0, (size_t)NV * 4, stream);
    csr_count_b<<<cdiv_i(dsc.totE, 256), 256, 0, stream>>>(dsc, cnt, pos);
    {
        const int nb = cdiv_i(NV, 1024);
        scan_tile<<<nb, 1024, 0, stream>>>(cnt, offs, bsum, NV, dsc.nbase[6],
                                           2 * NP, dinv);
        scan_single<<<1, 1024, 0, stream>>>(bsum, nb);
        scan_add<<<cdiv_i(NV + 1, 256), 256, 0, stream>>>(offs, bsum, NV, nb);
    }
    csr_fill_b<<<cdiv_i(totEntries, 256), 256, 0, stream>>>(dsc, offs, pos, cnt,
                                                            srcl, pedge, dinv,
                                                            left_x, right_x, mk,
                                                            NP, NV, pB);

    // ---- ontology: 2 GAT layers (transform-first, fused scores) ----
    GOnto go;
    go.Wt0 = wtOnt[0]; go.Wt1 = wtOnt[1]; go.Wt2 = wtOnt[2];
    go.s0 = ontAs[0]; go.s1 = ontAs[1]; go.s2 = ontAs[2];
    go.d0 = ontAd[0]; go.d1 = ontAd[1]; go.d2 = ontAd[2];
    go.bs1 = cdiv_i(Ms[0], 128);
    go.bs2 = go.bs1 + cdiv_i(Ms[1], 128);
    const int totBlk = go.bs2 + cdiv_i(Ms[2], 128);
    go.r1 = r1; go.r2 = r2; go.r3 = Mtot;

    for (int layer = 0; layer < 2; ++layer) {
        const GatP gp{r1, r2,
                      dsc.nbase[0 + layer], dsc.nbase[2 + layer], dsc.nbase[4 + layer],
                      ontB[0], ontB[1], ontB[2]};
        if (layer == 0)
            gemm_onto<float><<<totBlk, 256, 0, stream>>>(tabs[0], tabs[1], tabs[2],
                                                         go, hbuf, as, ad);
        else
            gemm_onto<ushort><<<totBlk, 256, 0, stream>>>(
                obuf, obuf + (size_t)r1 * HID, obuf + (size_t)r2 * HID,
                go, hbuf, as, ad);
        gat_all<<<cdiv_i(Mtot, 16), 256, 0, stream>>>(hbuf, as, ad, offs, srcl, gp,
                                                      obuf, Mtot);
    }

    EmbD ed;
    ed.spec = spec; ed.oE = obuf;
    ed.m0 = maps[0]; ed.m1 = maps[1]; ed.m2 = maps[2];
    ed.lb2 = 1 + Ls[0]; ed.lb3 = 1 + Ls[0] + Ls[1];
    ed.r1 = r1; ed.r2 = r2; ed.ALLr = ALL;
    build_emb<<<cdiv_i(ALL * 16, 256), 256, 0, stream>>>(ed, allemb);

    // ---- patient: folded GCN = 1 small GEMM + 3 sparsified aggregations ----
    const int* offs6 = offs + dsc.nbase[6];
    gemm_gcn<ushort><<<cdiv_i(ALL, 256), 256, 0, stream>>>(
        allemb, WpT, nullptr, A3, (int)ALL);
    gcn_agg1<<<cdiv_i(2 * NP, 16), 256, 0, stream>>>(A3, pedge, offs6, c1, t1,
                                                     list1, cnt12 + 0, pB);
    gcn_agg2<<<cdiv_i(2 * NP, 16), 256, 0, stream>>>(t1, pedge, offs6, c2, t2,
                                                     list2, cnt12 + 1, pB);
    gcn_final<<<cdiv_i(2 * B, 16), 256, 0, stream>>>(t2, pedge, offs6, gfL, gfR,
                                                     gcnB[2], lfrf, B, NP, pB);

    cosine_k<<<cdiv_i(B, 4), 256, 0, stream>>>(lfrf, (float*)d_out, B);
}

// Round 11
// 402.160 us; speedup vs baseline: 1.6870x; 1.6870x over previous
//
#include <hip/hip_runtime.h>
#include <hip/hip_bf16.h>

#define HID 128

typedef unsigned int uint;
typedef unsigned short ushort;
typedef short short8 __attribute__((ext_vector_type(8)));
typedef float f32x4 __attribute__((ext_vector_type(4)));

static inline int cdiv_i(long a, long b) { return (int)((a + b - 1) / b); }

__device__ __forceinline__ float bf2f(uint hi) {
    return __builtin_bit_cast(float, hi << 16);
}
__device__ __forceinline__ ushort f2bf(float f) {  // RNE
    uint u = __builtin_bit_cast(uint, f);
    u = (u + 0x7fffu + ((u >> 16) & 1u)) >> 16;
    return (ushort)u;
}

// ---------------------------------------------------------------------------
// Weight folding: Pout rows 0..127 = W1@W2@W3, row 128 = b1@W2@W3,
// row 129 = b2@W3 (augmented fp32 matmuls).
// ---------------------------------------------------------------------------
__global__ void build_aug(const float* __restrict__ W1, const float* __restrict__ b1,
                          const float* __restrict__ b2,
                          float* __restrict__ aug1, float* __restrict__ aug2) {
    const int i = blockIdx.x * 256 + threadIdx.x;
    if (i < 128 * 128) aug1[i] = W1[i];
    else if (i < 129 * 128) aug1[i] = b1[i - 128 * 128];
    if (i < 128) aug2[129 * 128 + i] = b2[i];
}

__global__ void matmul128f(const float* __restrict__ A, const float* __restrict__ B,
                           float* __restrict__ C, int M) {
    const int idx = blockIdx.x * 256 + threadIdx.x;
    if (idx >= M * 128) return;
    const int i = idx >> 7, j = idx & 127;
    float s = 0.f;
#pragma unroll 8
    for (int k = 0; k < 128; ++k) s += A[i * 128 + k] * B[k * 128 + j];
    C[idx] = s;
}

// ---------------------------------------------------------------------------
// Weight pre-transpose: Wt[m][n][k] = bf16(W[m][k][n]), 4 matrices.
// ---------------------------------------------------------------------------
struct W4 { const float* w[4]; };

__global__ void wtrans_k(W4 ws, ushort* __restrict__ out) {
    const int idx = blockIdx.x * 256 + threadIdx.x;
    if (idx >= 4 * 16384) return;
    const int m = idx >> 14;
    const int e = idx & 16383;
    const int n = e >> 7, k = e & 127;
    out[idx] = f2bf(ws.w[m][k * 128 + n]);
}

// ---------------------------------------------------------------------------
// MFMA GEMM machinery. Wt (bf16, [n][k]) staged to LDS stride 136, uint4 copy.
// ---------------------------------------------------------------------------
__device__ __forceinline__ void stage_wt(const ushort* __restrict__ Wt,
                                         ushort* __restrict__ wl) {
    const int t = threadIdx.x;
    const int row = t >> 1, half = (t & 1) * 64;
    const uint4* src = (const uint4*)(Wt + row * 128 + half);
    uint4* dst = (uint4*)(wl + row * 136 + half);
#pragma unroll
    for (int i = 0; i < 8; ++i) dst[i] = src[i];
}

template <typename AT>
__device__ __forceinline__ void load_afrag(const AT* __restrict__ A, long row,
                                           int koff, short8& af) {
    if constexpr (__is_same(AT, ushort)) {
        const uint4 raw = *(const uint4*)(A + row * 128 + koff);
        af = __builtin_bit_cast(short8, raw);
    } else {
        const float4* p = (const float4*)(A + row * 128 + koff);
        const float4 x0 = p[0], x1 = p[1];
        af[0] = (short)f2bf(x0.x); af[1] = (short)f2bf(x0.y);
        af[2] = (short)f2bf(x0.z); af[3] = (short)f2bf(x0.w);
        af[4] = (short)f2bf(x1.x); af[5] = (short)f2bf(x1.y);
        af[6] = (short)f2bf(x1.z); af[7] = (short)f2bf(x1.w);
    }
}

template <typename AT, typename OT>
__device__ __forceinline__ void mfma_tile(const AT* __restrict__ A,
                                          const ushort* __restrict__ wl,
                                          const float* __restrict__ bias,
                                          OT* __restrict__ C,
                                          long m0blk, long rowEnd) {
    const int tid = threadIdx.x;
    const int wave = tid >> 6, lane = tid & 63;
    const int r = lane & 15, q = lane >> 4;
    const long m0 = m0blk + wave * 32;

    f32x4 acc[2][8];
#pragma unroll
    for (int mi = 0; mi < 2; ++mi)
#pragma unroll
        for (int ni = 0; ni < 8; ++ni) acc[mi][ni] = (f32x4)0.f;

#pragma unroll
    for (int t = 0; t < 4; ++t) {
        const int koff = t * 32 + q * 8;
        short8 bfr[8];
#pragma unroll
        for (int ni = 0; ni < 8; ++ni) {
            const uint4 raw = *(const uint4*)(&wl[(ni * 16 + r) * 136 + koff]);
            bfr[ni] = __builtin_bit_cast(short8, raw);
        }
#pragma unroll
        for (int mi = 0; mi < 2; ++mi) {
            long row = m0 + mi * 16 + r;
            if (row >= rowEnd) row = rowEnd - 1;
            short8 af;
            load_afrag<AT>(A, row, koff, af);
#pragma unroll
            for (int ni = 0; ni < 8; ++ni)
                acc[mi][ni] = __builtin_amdgcn_mfma_f32_16x16x32_bf16(
                    af, bfr[ni], acc[mi][ni], 0, 0, 0);
        }
    }

#pragma unroll
    for (int mi = 0; mi < 2; ++mi) {
#pragma unroll
        for (int ni = 0; ni < 8; ++ni) {
            const int col = ni * 16 + r;
            const float bv = bias ? bias[col] : 0.f;
#pragma unroll
            for (int reg = 0; reg < 4; ++reg) {
                const long row = m0 + mi * 16 + q * 4 + reg;
                if (row < rowEnd) {
                    const float v = acc[mi][ni][reg] + bv;
                    if constexpr (__is_same(OT, ushort))
                        C[row * 128 + col] = f2bf(v);
                    else
                        C[row * 128 + col] = v;
                }
            }
        }
    }
}

template <typename OT>
__global__ __launch_bounds__(256) void gemm_gcn(const ushort* __restrict__ A,
                                                const ushort* __restrict__ Wt,
                                                const float* __restrict__ bias,
                                                OT* __restrict__ C, int M) {
    __shared__ ushort wl[128 * 136];
    stage_wt(Wt, wl);
    __syncthreads();
    const long m0 = (long)blockIdx.x * 256;
    mfma_tile<ushort, OT>(A, wl, bias, C, m0, M);
    if (m0 + 128 < M)
        mfma_tile<ushort, OT>(A, wl, bias, C, m0 + 128, M);
}

// ---------------------------------------------------------------------------
// Ontology GEMM with fused attention-score epilogue.
// ---------------------------------------------------------------------------
struct GOnto {
    const ushort* Wt0; const ushort* Wt1; const ushort* Wt2;
    const float* s0; const float* s1; const float* s2;
    const float* d0; const float* d1; const float* d2;
    int bs1, bs2;
    int r1, r2, r3;
};

template <typename AT>
__global__ __launch_bounds__(256) void gemm_onto(const AT* x0, const AT* x1,
                                                 const AT* x2, GOnto g,
                                                 ushort* __restrict__ H,
                                                 float* __restrict__ as_o,
                                                 float* __restrict__ ad_o) {
    __shared__ ushort wl[128 * 136];
    const int b = blockIdx.x;
    const int gid = (b >= g.bs1) + (b >= g.bs2);
    const ushort* Wt = (gid == 0) ? g.Wt0 : (gid == 1) ? g.Wt1 : g.Wt2;
    const float* avs = (gid == 0) ? g.s0 : (gid == 1) ? g.s1 : g.s2;
    const float* avd = (gid == 0) ? g.d0 : (gid == 1) ? g.d1 : g.d2;
    const AT* Ag = (gid == 0) ? x0 : (gid == 1) ? x1 : x2;
    const int bloc = b - ((gid == 0) ? 0 : (gid == 1) ? g.bs1 : g.bs2);
    const long rb = (gid == 0) ? 0 : (gid == 1) ? g.r1 : g.r2;
    const long Mg = ((gid == 0) ? g.r1 : (gid == 1) ? g.r2 : g.r3) - rb;
    stage_wt(Wt, wl);
    __syncthreads();

    const int tid = threadIdx.x;
    const int wave = tid >> 6, lane = tid & 63;
    const int r = lane & 15, q = lane >> 4;
    const long m0 = (long)bloc * 128 + wave * 32;

    f32x4 acc[2][8];
#pragma unroll
    for (int mi = 0; mi < 2; ++mi)
#pragma unroll
        for (int ni = 0; ni < 8; ++ni) acc[mi][ni] = (f32x4)0.f;

#pragma unroll
    for (int t = 0; t < 4; ++t) {
        const int koff = t * 32 + q * 8;
        short8 bfr[8];
#pragma unroll
        for (int ni = 0; ni < 8; ++ni) {
            const uint4 raw = *(const uint4*)(&wl[(ni * 16 + r) * 136 + koff]);
            bfr[ni] = __builtin_bit_cast(short8, raw);
        }
#pragma unroll
        for (int mi = 0; mi < 2; ++mi) {
            long row = m0 + mi * 16 + r;
            if (row >= Mg) row = Mg - 1;
            short8 af;
            load_afrag<AT>(Ag, row, koff, af);
#pragma unroll
            for (int ni = 0; ni < 8; ++ni)
                acc[mi][ni] = __builtin_amdgcn_mfma_f32_16x16x32_bf16(
                    af, bfr[ni], acc[mi][ni], 0, 0, 0);
        }
    }

    ushort* Hg = H + rb * 128;
#pragma unroll
    for (int mi = 0; mi < 2; ++mi) {
#pragma unroll
        for (int ni = 0; ni < 8; ++ni) {
            const int col = ni * 16 + r;
#pragma unroll
            for (int reg = 0; reg < 4; ++reg) {
                const long row = m0 + mi * 16 + q * 4 + reg;
                if (row < Mg) Hg[row * 128 + col] = f2bf(acc[mi][ni][reg]);
            }
        }
    }

    float asv[8], adv[8];
#pragma unroll
    for (int ni = 0; ni < 8; ++ni) {
        asv[ni] = avs[ni * 16 + r];
        adv[ni] = avd[ni * 16 + r];
    }
#pragma unroll
    for (int mi = 0; mi < 2; ++mi) {
#pragma unroll
        for (int reg = 0; reg < 4; ++reg) {
            float ps = 0.f, pd = 0.f;
#pragma unroll
            for (int ni = 0; ni < 8; ++ni) {
                ps += acc[mi][ni][reg] * asv[ni];
                pd += acc[mi][ni][reg] * adv[ni];
            }
#pragma unroll
            for (int o = 1; o < 16; o <<= 1) {
                ps += __shfl_xor(ps, o);
                pd += __shfl_xor(pd, o);
            }
            const long row = m0 + mi * 16 + q * 4 + reg;
            if (r == 0 && row < Mg) {
                as_o[rb + row] = ps;
                ad_o[rb + row] = pd;
            }
        }
    }
}

// ---------------------------------------------------------------------------
// GAT aggregation: quarter-wave per node.
// ---------------------------------------------------------------------------
struct GatP {
    int r1, r2;
    int ob0, ob1, ob2;
    const float* b0; const float* b1; const float* b2;
};

__device__ __forceinline__ void acc8(float* acc, float w, const uint4 v) {
    acc[0] += w * bf2f(v.x & 0xffff);
    acc[1] += w * bf2f(v.x >> 16);
    acc[2] += w * bf2f(v.y & 0xffff);
    acc[3] += w * bf2f(v.y >> 16);
    acc[4] += w * bf2f(v.z & 0xffff);
    acc[5] += w * bf2f(v.z >> 16);
    acc[6] += w * bf2f(v.w & 0xffff);
    acc[7] += w * bf2f(v.w >> 16);
}

__global__ __launch_bounds__(256) void gat_all(const ushort* __restrict__ h,
                                               const float* __restrict__ as,
                                               const float* __restrict__ ad,
                                               const int* __restrict__ offs,
                                               const int* __restrict__ srcl,
                                               GatP p, ushort* __restrict__ out,
                                               int Mtot) {
    const int node = blockIdx.x * 16 + (threadIdx.x >> 4);
    const int ql = threadIdx.x & 15;
    if (node >= Mtot) return;
    const int gid = (node >= p.r1) + (node >= p.r2);
    const int rb = (gid == 0) ? 0 : (gid == 1) ? p.r1 : p.r2;
    const int ob = (gid == 0) ? p.ob0 : (gid == 1) ? p.ob1 : p.ob2;
    const float* bias = (gid == 0) ? p.b0 : (gid == 1) ? p.b1 : p.b2;
    const int local = node - rb;
    const int beg = offs[ob + local], end = offs[ob + local + 1];
    const float adv = ad[node];
    float m = -1e30f;
    for (int j = beg; j < end; ++j) {
        float e = as[rb + srcl[j]] + adv;
        e = (e > 0.f) ? e : 0.2f * e;
        m = fmaxf(m, e);
    }
    float denom = 0.f;
    float acc[8] = {0.f, 0.f, 0.f, 0.f, 0.f, 0.f, 0.f, 0.f};
    int j = beg;
    for (; j + 2 <= end; j += 2) {
        const int s0 = srcl[j], s1 = srcl[j + 1];
        float e0 = as[rb + s0] + adv; e0 = (e0 > 0.f) ? e0 : 0.2f * e0;
        float e1 = as[rb + s1] + adv; e1 = (e1 > 0.f) ? e1 : 0.2f * e1;
        const float w0 = __expf(e0 - m), w1 = __expf(e1 - m);
        const uint4 v0 = *(const uint4*)(h + (size_t)(rb + s0) * 128 + ql * 8);
        const uint4 v1 = *(const uint4*)(h + (size_t)(rb + s1) * 128 + ql * 8);
        denom += w0 + w1;
        acc8(acc, w0, v0);
        acc8(acc, w1, v1);
    }
    if (j < end) {
        const int s0 = srcl[j];
        float e0 = as[rb + s0] + adv; e0 = (e0 > 0.f) ? e0 : 0.2f * e0;
        const float w0 = __expf(e0 - m);
        const uint4 v0 = *(const uint4*)(h + (size_t)(rb + s0) * 128 + ql * 8);
        denom += w0;
        acc8(acc, w0, v0);
    }
    const float inv = 1.f / denom;
    const float4 bv0 = *(const float4*)(bias + ql * 8);
    const float4 bv1 = *(const float4*)(bias + ql * 8 + 4);
    uint4 o;
    o.x = (uint)f2bf(acc[0] * inv + bv0.x) | ((uint)f2bf(acc[1] * inv + bv0.y) << 16);
    o.y = (uint)f2bf(acc[2] * inv + bv0.z) | ((uint)f2bf(acc[3] * inv + bv0.w) << 16);
    o.z = (uint)f2bf(acc[4] * inv + bv1.x) | ((uint)f2bf(acc[5] * inv + bv1.y) << 16);
    o.w = (uint)f2bf(acc[6] * inv + bv1.z) | ((uint)f2bf(acc[7] * inv + bv1.w) << 16);
    *(uint4*)(out + (size_t)node * 128 + ql * 8) = o;
}

// ---------------------------------------------------------------------------
// Batched CSR build (8 lists; self-loops atomic-free in reserved last slot).
// Patient slots -> int4 record {src, gxi, nw_bits, 0}, written ONLY for dst
// nodes whose edge lists will actually be read (mk != 0).
// ---------------------------------------------------------------------------
struct CsrDesc {
    const int* esrc[8];
    const int* edst[8];
    int ebase[9];
    int nbase[9];
    int totE;
};

__global__ void csr_count_b(CsrDesc d, int* __restrict__ cnt, int* __restrict__ pos) {
    const int i = blockIdx.x * 256 + threadIdx.x;
    if (i >= d.totE) return;
    int li = 0;
#pragma unroll
    for (int k = 1; k < 8; ++k) li += (i >= d.ebase[k]);
    const int v = d.nbase[li] + d.edst[li][i - d.ebase[li]];
    pos[i] = atomicAdd(&cnt[v], 1);
}

__global__ void csr_fill_b(CsrDesc d, const int* __restrict__ offs,
                           const int* __restrict__ pos, const int* __restrict__ cnt,
                           int* __restrict__ srcl, int4* __restrict__ pedge,
                           const float* __restrict__ dinv,
                           const int* __restrict__ lx, const int* __restrict__ rx,
                           const int* __restrict__ mk,
                           int NP, int NV, int pB) {
    const int i = blockIdx.x * 256 + threadIdx.x;
    int v, s, li, idx;
    if (i < d.totE) {
        li = 0;
#pragma unroll
        for (int k = 1; k < 8; ++k) li += (i >= d.ebase[k]);
        const int j = i - d.ebase[li];
        v = d.nbase[li] + d.edst[li][j];
        s = d.esrc[li][j];
        idx = offs[v] + pos[i];
    } else if (i < d.totE + NV) {
        v = i - d.totE;
        li = 0;
#pragma unroll
        for (int k = 1; k < 8; ++k) li += (v >= d.nbase[k]);
        s = v - d.nbase[li];
        idx = offs[v] + cnt[v];
    } else return;
    if (li >= 6) {
        const int n2l = v - d.nbase[6];
        if (mk[n2l] == 0) return;   // edge list never read
        const int sg = (li - 6) * NP + s;
        int4 rec;
        rec.x = sg;
        rec.y = (li == 7 ? rx : lx)[s];
        rec.z = __float_as_int(dinv[n2l] * dinv[sg]);
        rec.w = 0;
        pedge[idx - pB] = rec;
    } else {
        srcl[idx] = s;
    }
}

// First node of each graph (sorted batch); sets fin bit (1) in mk.
__global__ void first_node(const int* __restrict__ bL, const int* __restrict__ bR,
                           int NP, int* __restrict__ gfL, int* __restrict__ gfR,
                           int* __restrict__ mk) {
    const int i = blockIdx.x * 256 + threadIdx.x;
    if (i >= 2 * NP) return;
    const int side = i >= NP;
    const int ii = i - (side ? NP : 0);
    const int* b = side ? bR : bL;
    int* gf = side ? gfR : gfL;
    const int cur = b[ii];
    const int prev = (ii == 0) ? -1 : b[ii - 1];
    if (cur > prev) {
        for (int g = prev + 1; g <= cur; ++g) gf[g] = ii;
        mk[i] = 1;
    }
}

// ---------------------------------------------------------------------------
// Backward reachability marking over raw patient edge lists.
// mk bits: 1 = final node, 2 = needed in t2, 4 = needed in t1.
// NON-RETURNING atomicOr only — no single-address append (G12).
// ---------------------------------------------------------------------------
__global__ void mark_k(const int* __restrict__ lEg, const int* __restrict__ rEg,
                       int EP, int NP, int* __restrict__ mk, int testBit, int setBit) {
    const int i = blockIdx.x * 256 + threadIdx.x;
    int src, dst;
    if (i < 2 * EP) {
        const int side = i >= EP;
        const int e = i - side * EP;
        const int* eg = side ? rEg : lEg;
        src = side * NP + eg[e];
        dst = side * NP + eg[EP + e];
    } else if (i < 2 * EP + 2 * NP) {
        src = dst = i - 2 * EP;   // self-loop
    } else return;
    if (mk[dst] & testBit) atomicOr(&mk[src], setBit);
}

// ---------------------------------------------------------------------------
// 3-phase exclusive scan over (cnt[v]+1); emits dinv for the patient range.
// ---------------------------------------------------------------------------
__global__ __launch_bounds__(1024) void scan_tile(const int* __restrict__ in,
                                                  int* __restrict__ out,
                                                  int* __restrict__ bsum, int n,
                                                  int pn0, int pcnt,
                                                  float* __restrict__ dinv) {
    __shared__ int buf[1024];
    const int tid = threadIdx.x;
    const int i = blockIdx.x * 1024 + tid;
    const int v = (i < n) ? (in[i] + 1) : 0;
    if (i >= pn0 && i < pn0 + pcnt)
        dinv[i - pn0] = rsqrtf(fmaxf((float)v, 1e-12f));
    buf[tid] = v;
    __syncthreads();
    int x = v;
    for (int o = 1; o < 1024; o <<= 1) {
        const int t = (tid >= o) ? buf[tid - o] : 0;
        __syncthreads();
        x += t;
        buf[tid] = x;
        __syncthreads();
    }
    if (i < n) out[i] = x - v;
    if (tid == 1023) bsum[blockIdx.x] = x;
}

__global__ __launch_bounds__(1024) void scan_single(int* __restrict__ bsum, int nb) {
    __shared__ int buf[1024];
    const int tid = threadIdx.x;
    const int v = (tid < nb) ? bsum[tid] : 0;
    buf[tid] = v;
    __syncthreads();
    int x = v;
    for (int o = 1; o < 1024; o <<= 1) {
        const int t = (tid >= o) ? buf[tid - o] : 0;
        __syncthreads();
        x += t;
        buf[tid] = x;
        __syncthreads();
    }
    if (tid < nb) bsum[tid] = x - v;
    if (tid == 1023) bsum[nb] = x;
}

__global__ void scan_add(int* __restrict__ out, const int* __restrict__ bsum,
                         int n, int nb) {
    const int i = blockIdx.x * 256 + threadIdx.x;
    if (i < n) out[i] += bsum[i >> 10];
    else if (i == n) out[i] = bsum[nb];
}

// ---------------------------------------------------------------------------
// allemb (bf16): row 0 = spec (fp32 src), then 3 ontology maps from bf16 oE.
// ---------------------------------------------------------------------------
struct EmbD {
    const float* spec; const ushort* oE;
    const int* m0; const int* m1; const int* m2;
    int lb2, lb3;
    int r1, r2;
    long ALLr;
};

__global__ void build_emb(EmbD d, ushort* __restrict__ out) {
    const long t = (long)blockIdx.x * 256 + threadIdx.x;
    if (t >= d.ALLr * 16) return;
    const int row = (int)(t >> 4), c = (int)(t & 15);
    uint4 o;
    if (row == 0) {
        const float4 f0 = ((const float4*)d.spec)[c * 2];
        const float4 f1 = ((const float4*)d.spec)[c * 2 + 1];
        o.x = (uint)f2bf(f0.x) | ((uint)f2bf(f0.y) << 16);
        o.y = (uint)f2bf(f0.z) | ((uint)f2bf(f0.w) << 16);
        o.z = (uint)f2bf(f1.x) | ((uint)f2bf(f1.y) << 16);
        o.w = (uint)f2bf(f1.z) | ((uint)f2bf(f1.w) << 16);
    } else {
        const int seg = (row >= d.lb2) + (row >= d.lb3);
        const int local = row - ((seg == 0) ? 1 : (seg == 1) ? d.lb2 : d.lb3);
        const int* mp = (seg == 0) ? d.m0 : (seg == 1) ? d.m1 : d.m2;
        const int rb = (seg == 0) ? 0 : (seg == 1) ? d.r1 : d.r2;
        o = ((const uint4*)(d.oE + (size_t)(rb + mp[local]) * 128))[c];
    }
    ((uint4*)out)[(size_t)row * 16 + c] = o;
}

// ---------------------------------------------------------------------------
// GCN aggregations: quarter-wave per node, early exit on mk bit.
// Edge record = int4 {src, gxi, nw, 0}.
// ---------------------------------------------------------------------------
__global__ __launch_bounds__(256) void gcn_agg1(const ushort* __restrict__ A3,
                                                const int4* __restrict__ pedge,
                                                const int* __restrict__ offs6,
                                                const float* __restrict__ c1,
                                                ushort* __restrict__ t1,
                                                const int* __restrict__ mk,
                                                int NP2, int pB) {
    const int n2 = blockIdx.x * 16 + (threadIdx.x >> 4);
    const int ql = threadIdx.x & 15;
    if (n2 >= NP2) return;
    if ((mk[n2] & 4) == 0) return;   // t1 row never read
    const int beg = offs6[n2] - pB, end = offs6[n2 + 1] - pB;
    float acc[8] = {0.f, 0.f, 0.f, 0.f, 0.f, 0.f, 0.f, 0.f};
    int j = beg;
    for (; j + 2 <= end; j += 2) {
        const int4 r0 = pedge[j], r1 = pedge[j + 1];
        const float w0 = __int_as_float(r0.z), w1 = __int_as_float(r1.z);
        const uint4 v0 = *(const uint4*)(A3 + (size_t)r0.y * 128 + ql * 8);
        const uint4 v1 = *(const uint4*)(A3 + (size_t)r1.y * 128 + ql * 8);
        acc8(acc, w0, v0);
        acc8(acc, w1, v1);
    }
    if (j < end) {
        const int4 r0 = pedge[j];
        const uint4 v0 = *(const uint4*)(A3 + (size_t)r0.y * 128 + ql * 8);
        acc8(acc, __int_as_float(r0.z), v0);
    }
    const float4 bv0 = *(const float4*)(c1 + ql * 8);
    const float4 bv1 = *(const float4*)(c1 + ql * 8 + 4);
    uint4 o;
    o.x = (uint)f2bf(acc[0] + bv0.x) | ((uint)f2bf(acc[1] + bv0.y) << 16);
    o.y = (uint)f2bf(acc[2] + bv0.z) | ((uint)f2bf(acc[3] + bv0.w) << 16);
    o.z = (uint)f2bf(acc[4] + bv1.x) | ((uint)f2bf(acc[5] + bv1.y) << 16);
    o.w = (uint)f2bf(acc[6] + bv1.z) | ((uint)f2bf(acc[7] + bv1.w) << 16);
    *(uint4*)(t1 + (size_t)n2 * 128 + ql * 8) = o;
}

__device__ __forceinline__ void gcn_q_acc(const ushort* __restrict__ x,
                                          const int4* __restrict__ pedge,
                                          int beg, int end, int ql, float* acc) {
    int j = beg;
    for (; j + 2 <= end; j += 2) {
        const int4 r0 = pedge[j], r1 = pedge[j + 1];
        const float w0 = __int_as_float(r0.z), w1 = __int_as_float(r1.z);
        const uint4 v0 = *(const uint4*)(x + (size_t)r0.x * 128 + ql * 8);
        const uint4 v1 = *(const uint4*)(x + (size_t)r1.x * 128 + ql * 8);
        acc8(acc, w0, v0);
        acc8(acc, w1, v1);
    }
    if (j < end) {
        const int4 r0 = pedge[j];
        const uint4 v0 = *(const uint4*)(x + (size_t)r0.x * 128 + ql * 8);
        acc8(acc, __int_as_float(r0.z), v0);
    }
}

__global__ __launch_bounds__(256) void gcn_agg2(const ushort* __restrict__ t1,
                                                const int4* __restrict__ pedge,
                                                const int* __restrict__ offs6,
                                                const float* __restrict__ c2,
                                                ushort* __restrict__ t2,
                                                const int* __restrict__ mk,
                                                int NP2, int pB) {
    const int n2 = blockIdx.x * 16 + (threadIdx.x >> 4);
    const int ql = threadIdx.x & 15;
    if (n2 >= NP2) return;
    if ((mk[n2] & 2) == 0) return;   // t2 row never read
    const int beg = offs6[n2] - pB, end = offs6[n2 + 1] - pB;
    float acc[8] = {0.f, 0.f, 0.f, 0.f, 0.f, 0.f, 0.f, 0.f};
    gcn_q_acc(t1, pedge, beg, end, ql, acc);
    const float4 bv0 = *(const float4*)(c2 + ql * 8);
    const float4 bv1 = *(const float4*)(c2 + ql * 8 + 4);
    uint4 o;
    o.x = (uint)f2bf(acc[0] + bv0.x) | ((uint)f2bf(acc[1] + bv0.y) << 16);
    o.y = (uint)f2bf(acc[2] + bv0.z) | ((uint)f2bf(acc[3] + bv0.w) << 16);
    o.z = (uint)f2bf(acc[4] + bv1.x) | ((uint)f2bf(acc[5] + bv1.y) << 16);
    o.w = (uint)f2bf(acc[6] + bv1.z) | ((uint)f2bf(acc[7] + bv1.w) << 16);
    *(uint4*)(t2 + (size_t)n2 * 128 + ql * 8) = o;
}

// Layer 3: aggregate only final nodes; +b3; fp32 output straight to lfrf.
__global__ __launch_bounds__(256) void gcn_final(const ushort* __restrict__ t2,
                                                 const int4* __restrict__ pedge,
                                                 const int* __restrict__ offs6,
                                                 const int* __restrict__ gfL,
                                                 const int* __restrict__ gfR,
                                                 const float* __restrict__ b3,
                                                 float* __restrict__ lfrf,
                                                 int B, int NP, int pB) {
    const int g2 = blockIdx.x * 16 + (threadIdx.x >> 4);
    const int ql = threadIdx.x & 15;
    if (g2 >= 2 * B) return;
    const int side = g2 >= B;
    const int gl = g2 - (side ? B : 0);
    const int n2 = (side ? NP : 0) + (side ? gfR : gfL)[gl];
    const int beg = offs6[n2] - pB, end = offs6[n2 + 1] - pB;
    float acc[8] = {0.f, 0.f, 0.f, 0.f, 0.f, 0.f, 0.f, 0.f};
    gcn_q_acc(t2, pedge, beg, end, ql, acc);
    const float4 bv0 = *(const float4*)(b3 + ql * 8);
    const float4 bv1 = *(const float4*)(b3 + ql * 8 + 4);
    float* op = lfrf + (size_t)g2 * 128 + ql * 8;
    op[0] = acc[0] + bv0.x; op[1] = acc[1] + bv0.y;
    op[2] = acc[2] + bv0.z; op[3] = acc[3] + bv0.w;
    op[4] = acc[4] + bv1.x; op[5] = acc[5] + bv1.y;
    op[6] = acc[6] + bv1.z; op[7] = acc[7] + bv1.w;
}

// ---------------------------------------------------------------------------
// Cosine similarity: lfrf holds left rows [0,B), right rows [B,2B).
// ---------------------------------------------------------------------------
__global__ __launch_bounds__(256) void cosine_k(const float* __restrict__ lfrf,
                                                float* __restrict__ out, int B) {
    const int g = blockIdx.x * 4 + (threadIdx.x >> 6);
    const int lane = threadIdx.x & 63;
    if (g >= B) return;
    const float2 a = *(const float2*)(lfrf + (size_t)g * 128 + lane * 2);
    const float2 b = *(const float2*)(lfrf + (size_t)(B + g) * 128 + lane * 2);
    float num = a.x * b.x + a.y * b.y;
    float na = a.x * a.x + a.y * a.y;
    float nb = b.x * b.x + b.y * b.y;
#pragma unroll
    for (int o = 32; o > 0; o >>= 1) {
        num += __shfl_down(num, o);
        na += __shfl_down(na, o);
        nb += __shfl_down(nb, o);
    }
    if (lane == 0)
        out[g] = num / (fmaxf(sqrtf(na), 1e-6f) * fmaxf(sqrtf(nb), 1e-6f));
}

// ---------------------------------------------------------------------------
extern "C" void kernel_launch(void* const* d_in, const int* in_sizes, int n_in,
                              void* d_out, int out_size, void* d_ws, size_t ws_size,
                              hipStream_t stream) {
    (void)n_in; (void)ws_size;
    // setup_inputs() dict order
    const float* spec = (const float*)d_in[0];
    const float* tabs[3] = {(const float*)d_in[1], (const float*)d_in[2], (const float*)d_in[3]};
    const float* ontW[3] = {(const float*)d_in[4], (const float*)d_in[8], (const float*)d_in[12]};
    const float* ontAs[3] = {(const float*)d_in[5], (const float*)d_in[9], (const float*)d_in[13]};
    const float* ontAd[3] = {(const float*)d_in[6], (const float*)d_in[10], (const float*)d_in[14]};
    const float* ontB[3] = {(const float*)d_in[7], (const float*)d_in[11], (const float*)d_in[15]};
    const float* gcnW[3] = {(const float*)d_in[16], (const float*)d_in[18], (const float*)d_in[20]};
    const float* gcnB[3] = {(const float*)d_in[17], (const float*)d_in[19], (const float*)d_in[21]};
    const int* e1s[3] = {(const int*)d_in[22], (const int*)d_in[24], (const int*)d_in[26]};
    const int* e2s[3] = {(const int*)d_in[23], (const int*)d_in[25], (const int*)d_in[27]};
    const int* maps[3] = {(const int*)d_in[28], (const int*)d_in[29], (const int*)d_in[30]};
    const int* left_x = (const int*)d_in[31];
    const int* right_x = (const int*)d_in[32];
    const int* left_eg = (const int*)d_in[33];
    const int* right_eg = (const int*)d_in[34];
    const int* left_batch = (const int*)d_in[35];
    const int* right_batch = (const int*)d_in[36];

    int Ms[3] = {in_sizes[1] / HID, in_sizes[2] / HID, in_sizes[3] / HID};
    int E1s[3] = {in_sizes[22] / 2, in_sizes[24] / 2, in_sizes[26] / 2};
    int E2s[3] = {in_sizes[23] / 2, in_sizes[25] / 2, in_sizes[27] / 2};
    int Ls[3] = {in_sizes[28], in_sizes[29], in_sizes[30]};
    const int NP = in_sizes[31];
    const int EP = in_sizes[33] / 2;
    const int B = out_size;
    const long ALL = 1 + (long)Ls[0] + Ls[1] + Ls[2];
    const int Mtot = Ms[0] + Ms[1] + Ms[2];
    const int r1 = Ms[0], r2 = Ms[0] + Ms[1];

    // ---- batched CSR descriptor (8 lists; self-loops implicit) ----
    CsrDesc dsc;
    int eCnt[8], nCnt[8];
    for (int i = 0; i < 3; ++i) {
        dsc.esrc[2 * i] = e1s[i];     dsc.edst[2 * i] = e1s[i] + E1s[i];
        dsc.esrc[2 * i + 1] = e2s[i]; dsc.edst[2 * i + 1] = e2s[i] + E2s[i];
        eCnt[2 * i] = E1s[i]; eCnt[2 * i + 1] = E2s[i];
        nCnt[2 * i] = Ms[i];  nCnt[2 * i + 1] = Ms[i];
    }
    dsc.esrc[6] = left_eg;  dsc.edst[6] = left_eg + EP;  eCnt[6] = EP; nCnt[6] = NP;
    dsc.esrc[7] = right_eg; dsc.edst[7] = right_eg + EP; eCnt[7] = EP; nCnt[7] = NP;
    dsc.ebase[0] = 0;
    int nb_acc = 0;
    for (int i = 0; i < 8; ++i) {
        dsc.ebase[i + 1] = dsc.ebase[i] + eCnt[i];
        dsc.nbase[i] = nb_acc;
        nb_acc += nCnt[i];
    }
    const int NV = nb_acc;
    dsc.nbase[8] = NV;
    dsc.totE = dsc.ebase[8];
    const int totEntries = dsc.totE + NV;
    const int pB = dsc.ebase[6] + dsc.nbase[6];
    const int pEntries = totEntries - pB;

    // ---- workspace layout ----
    char* ws = (char*)d_ws;
    size_t off = 0;
    auto alloc = [&](size_t bytes) -> void* {
        off = (off + 255) & ~(size_t)255;
        void* p = ws + off;
        off += bytes;
        return p;
    };
    ushort* wt4 = (ushort*)alloc((size_t)4 * 16384 * 2);   // 3 ont Wt + WpT
    float* aug1 = (float*)alloc((size_t)130 * 128 * 4);
    float* aug2 = (float*)alloc((size_t)130 * 128 * 4);
    float* Pout = (float*)alloc((size_t)130 * 128 * 4);
    ushort* allemb = (ushort*)alloc((size_t)ALL * HID * 2);
    ushort* A3 = (ushort*)alloc((size_t)ALL * HID * 2);
    float* lfrf = (float*)alloc((size_t)2 * B * HID * 4);
    int* cnt = (int*)alloc((size_t)NV * 4);
    int* offs = (int*)alloc((size_t)(NV + 1) * 4);
    int* pos = (int*)alloc((size_t)dsc.totE * 4);
    int* srcl = (int*)alloc((size_t)pB * 4);
    int4* pedge = (int4*)alloc((size_t)pEntries * 16);
    int* bsum = (int*)alloc(1025 * 4);
    float* dinv = (float*)alloc((size_t)2 * NP * 4);
    float* as = (float*)alloc((size_t)Mtot * 4);
    float* ad = (float*)alloc((size_t)Mtot * 4);
    int* gfL = (int*)alloc((size_t)(B + 1) * 4);
    int* gfR = (int*)alloc((size_t)(B + 1) * 4);
    int* mk = (int*)alloc((size_t)2 * NP * 4);
    ushort* t1 = (ushort*)alloc((size_t)2 * NP * HID * 2);
    // big region: ontology hbuf/obuf first, then t2
    ushort* big = (ushort*)alloc((size_t)2 * NP * HID * 2);
    ushort* hbuf = big;                              // [Mtot x 128] bf16
    ushort* obuf = big + (size_t)Mtot * HID;         // [Mtot x 128] bf16
    ushort* t2 = big;                                // [2NP x 128] bf16 (later)

    // ---- weight folding: Pout = [W1;b1;b2-aug] @ W2 @ W3 ----
    build_aug<<<cdiv_i(129 * 128, 256), 256, 0, stream>>>(gcnW[0], gcnB[0], gcnB[1],
                                                          aug1, aug2);
    matmul128f<<<cdiv_i(129 * 128, 256), 256, 0, stream>>>(aug1, gcnW[1], aug2, 129);
    matmul128f<<<cdiv_i(130 * 128, 256), 256, 0, stream>>>(aug2, gcnW[2], Pout, 130);
    const float* c1 = Pout + 128 * 128;
    const float* c2 = Pout + 129 * 128;

    // ---- weight transpose (bf16): 3 ont + folded Wp ----
    W4 w4;
    w4.w[0] = ontW[0]; w4.w[1] = ontW[1]; w4.w[2] = ontW[2]; w4.w[3] = Pout;
    wtrans_k<<<cdiv_i(4 * 16384, 256), 256, 0, stream>>>(w4, wt4);
    const ushort* wtOnt[3] = {wt4, wt4 + 16384, wt4 + 2 * 16384};
    const ushort* WpT = wt4 + 3 * 16384;

    // ---- backward reachability marks (raw edges; non-returning atomics) ----
    hipMemsetAsync(mk, 0, (size_t)2 * NP * 4, stream);
    first_node<<<cdiv_i(2 * NP, 256), 256, 0, stream>>>(left_batch, right_batch,
                                                        NP, gfL, gfR, mk);
    mark_k<<<cdiv_i(2 * EP + 2 * NP, 256), 256, 0, stream>>>(
        left_eg, right_eg, EP, NP, mk, 1, 2);
    mark_k<<<cdiv_i(2 * EP + 2 * NP, 256), 256, 0, stream>>>(
        left_eg, right_eg, EP, NP, mk, 2, 4);

    // ---- CSR build ----
    hipMemsetAsync(cnt, 0, (size_t)NV * 4, stream);
    csr_count_b<<<cdiv_i(dsc.totE, 256), 256, 0, stream>>>(dsc, cnt, pos);
    {
        const int nb = cdiv_i(NV, 1024);
        scan_tile<<<nb, 1024, 0, stream>>>(cnt, offs, bsum, NV, dsc.nbase[6],
                                           2 * NP, dinv);
        scan_single<<<1, 1024, 0, stream>>>(bsum, nb);
        scan_add<<<cdiv_i(NV + 1, 256), 256, 0, stream>>>(offs, bsum, NV, nb);
    }
    csr_fill_b<<<cdiv_i(totEntries, 256), 256, 0, stream>>>(dsc, offs, pos, cnt,
                                                            srcl, pedge, dinv,
                                                            left_x, right_x, mk,
                                                            NP, NV, pB);

    // ---- ontology: 2 GAT layers (transform-first, fused scores) ----
    GOnto go;
    go.Wt0 = wtOnt[0]; go.Wt1 = wtOnt[1]; go.Wt2 = wtOnt[2];
    go.s0 = ontAs[0]; go.s1 = ontAs[1]; go.s2 = ontAs[2];
    go.d0 = ontAd[0]; go.d1 = ontAd[1]; go.d2 = ontAd[2];
    go.bs1 = cdiv_i(Ms[0], 128);
    go.bs2 = go.bs1 + cdiv_i(Ms[1], 128);
    const int totBlk = go.bs2 + cdiv_i(Ms[2], 128);
    go.r1 = r1; go.r2 = r2; go.r3 = Mtot;

    for (int layer = 0; layer < 2; ++layer) {
        const GatP gp{r1, r2,
                      dsc.nbase[0 + layer], dsc.nbase[2 + layer], dsc.nbase[4 + layer],
                      ontB[0], ontB[1], ontB[2]};
        if (layer == 0)
            gemm_onto<float><<<totBlk, 256, 0, stream>>>(tabs[0], tabs[1], tabs[2],
                                                         go, hbuf, as, ad);
        else
            gemm_onto<ushort><<<totBlk, 256, 0, stream>>>(
                obuf, obuf + (size_t)r1 * HID, obuf + (size_t)r2 * HID,
                go, hbuf, as, ad);
        gat_all<<<cdiv_i(Mtot, 16), 256, 0, stream>>>(hbuf, as, ad, offs, srcl, gp,
                                                      obuf, Mtot);
    }

    EmbD ed;
    ed.spec = spec; ed.oE = obuf;
    ed.m0 = maps[0]; ed.m1 = maps[1]; ed.m2 = maps[2];
    ed.lb2 = 1 + Ls[0]; ed.lb3 = 1 + Ls[0] + Ls[1];
    ed.r1 = r1; ed.r2 = r2; ed.ALLr = ALL;
    build_emb<<<cdiv_i(ALL * 16, 256), 256, 0, stream>>>(ed, allemb);

    // ---- patient: folded GCN = 1 small GEMM + 3 sparsified aggregations ----
    const int* offs6 = offs + dsc.nbase[6];
    gemm_gcn<ushort><<<cdiv_i(ALL, 256), 256, 0, stream>>>(
        allemb, WpT, nullptr, A3, (int)ALL);
    gcn_agg1<<<cdiv_i(2 * NP, 16), 256, 0, stream>>>(A3, pedge, offs6, c1, t1,
                                                     mk, 2 * NP, pB);
    gcn_agg2<<<cdiv_i(2 * NP, 16), 256, 0, stream>>>(t1, pedge, offs6, c2, t2,
                                                     mk, 2 * NP, pB);
    gcn_final<<<cdiv_i(2 * B, 16), 256, 0, stream>>>(t2, pedge, offs6, gfL, gfR,
                                                     gcnB[2], lfrf, B, NP, pB);

    cosine_k<<<cdiv_i(B, 4), 256, 0, stream>>>(lfrf, (float*)d_out, B);
}

// Round 13
// 393.142 us; speedup vs baseline: 1.7257x; 1.0229x over previous
//
#include <hip/hip_runtime.h>
#include <hip/hip_bf16.h>

#define HID 128

typedef unsigned int uint;
typedef unsigned short ushort;
typedef short short8 __attribute__((ext_vector_type(8)));
typedef float f32x4 __attribute__((ext_vector_type(4)));

static inline int cdiv_i(long a, long b) { return (int)((a + b - 1) / b); }

__device__ __forceinline__ float bf2f(uint hi) {
    return __builtin_bit_cast(float, hi << 16);
}
__device__ __forceinline__ ushort f2bf(float f) {  // RNE
    uint u = __builtin_bit_cast(uint, f);
    u = (u + 0x7fffu + ((u >> 16) & 1u)) >> 16;
    return (ushort)u;
}

// ---------------------------------------------------------------------------
// Weight folding, 2 launches:
// fold1: W23b[129][128] = [W2; b2] @ W3
// fold2: Pout rows 0..128 = [W1; b1] @ W23b(0..127), row 129 = W23b row 128.
// => Pout: 0..127 = W1W2W3, 128 = b1W2W3 (c1), 129 = b2W3 (c2).
// ---------------------------------------------------------------------------
__global__ void fold1(const float* __restrict__ W2, const float* __restrict__ b2,
                      const float* __restrict__ W3, float* __restrict__ W23b) {
    const int idx = blockIdx.x * 256 + threadIdx.x;
    if (idx >= 129 * 128) return;
    const int i = idx >> 7, j = idx & 127;
    const float* a = (i < 128) ? (W2 + i * 128) : b2;
    float s = 0.f;
#pragma unroll 8
    for (int k = 0; k < 128; ++k) s += a[k] * W3[k * 128 + j];
    W23b[idx] = s;
}

__global__ void fold2(const float* __restrict__ W1, const float* __restrict__ b1,
                      const float* __restrict__ W23b, float* __restrict__ Pout) {
    const int idx = blockIdx.x * 256 + threadIdx.x;
    if (idx >= 130 * 128) return;
    const int i = idx >> 7, j = idx & 127;
    if (i == 129) { Pout[idx] = W23b[128 * 128 + j]; return; }
    const float* a = (i < 128) ? (W1 + i * 128) : b1;
    float s = 0.f;
#pragma unroll 8
    for (int k = 0; k < 128; ++k) s += a[k] * W23b[k * 128 + j];
    Pout[idx] = s;
}

// ---------------------------------------------------------------------------
// Weight pre-transpose: Wt[m][n][k] = bf16(W[m][k][n]), 4 matrices.
// ---------------------------------------------------------------------------
struct W4 { const float* w[4]; };

__global__ void wtrans_k(W4 ws, ushort* __restrict__ out) {
    const int idx = blockIdx.x * 256 + threadIdx.x;
    if (idx >= 4 * 16384) return;
    const int m = idx >> 14;
    const int e = idx & 16383;
    const int n = e >> 7, k = e & 127;
    out[idx] = f2bf(ws.w[m][k * 128 + n]);
}

// ---------------------------------------------------------------------------
// MFMA GEMM machinery. Wt (bf16, [n][k]) staged to LDS stride 136, uint4 copy.
// ---------------------------------------------------------------------------
__device__ __forceinline__ void stage_wt(const ushort* __restrict__ Wt,
                                         ushort* __restrict__ wl) {
    const int t = threadIdx.x;
    const int row = t >> 1, half = (t & 1) * 64;
    const uint4* src = (const uint4*)(Wt + row * 128 + half);
    uint4* dst = (uint4*)(wl + row * 136 + half);
#pragma unroll
    for (int i = 0; i < 8; ++i) dst[i] = src[i];
}

template <typename AT>
__device__ __forceinline__ void load_afrag(const AT* __restrict__ A, long row,
                                           int koff, short8& af) {
    if constexpr (__is_same(AT, ushort)) {
        const uint4 raw = *(const uint4*)(A + row * 128 + koff);
        af = __builtin_bit_cast(short8, raw);
    } else {
        const float4* p = (const float4*)(A + row * 128 + koff);
        const float4 x0 = p[0], x1 = p[1];
        af[0] = (short)f2bf(x0.x); af[1] = (short)f2bf(x0.y);
        af[2] = (short)f2bf(x0.z); af[3] = (short)f2bf(x0.w);
        af[4] = (short)f2bf(x1.x); af[5] = (short)f2bf(x1.y);
        af[6] = (short)f2bf(x1.z); af[7] = (short)f2bf(x1.w);
    }
}

template <typename AT, typename OT>
__device__ __forceinline__ void mfma_tile(const AT* __restrict__ A,
                                          const ushort* __restrict__ wl,
                                          const float* __restrict__ bias,
                                          OT* __restrict__ C,
                                          long m0blk, long rowEnd) {
    const int tid = threadIdx.x;
    const int wave = tid >> 6, lane = tid & 63;
    const int r = lane & 15, q = lane >> 4;
    const long m0 = m0blk + wave * 32;

    f32x4 acc[2][8];
#pragma unroll
    for (int mi = 0; mi < 2; ++mi)
#pragma unroll
        for (int ni = 0; ni < 8; ++ni) acc[mi][ni] = (f32x4)0.f;

#pragma unroll
    for (int t = 0; t < 4; ++t) {
        const int koff = t * 32 + q * 8;
        short8 bfr[8];
#pragma unroll
        for (int ni = 0; ni < 8; ++ni) {
            const uint4 raw = *(const uint4*)(&wl[(ni * 16 + r) * 136 + koff]);
            bfr[ni] = __builtin_bit_cast(short8, raw);
        }
#pragma unroll
        for (int mi = 0; mi < 2; ++mi) {
            long row = m0 + mi * 16 + r;
            if (row >= rowEnd) row = rowEnd - 1;
            short8 af;
            load_afrag<AT>(A, row, koff, af);
#pragma unroll
            for (int ni = 0; ni < 8; ++ni)
                acc[mi][ni] = __builtin_amdgcn_mfma_f32_16x16x32_bf16(
                    af, bfr[ni], acc[mi][ni], 0, 0, 0);
        }
    }

#pragma unroll
    for (int mi = 0; mi < 2; ++mi) {
#pragma unroll
        for (int ni = 0; ni < 8; ++ni) {
            const int col = ni * 16 + r;
            const float bv = bias ? bias[col] : 0.f;
#pragma unroll
            for (int reg = 0; reg < 4; ++reg) {
                const long row = m0 + mi * 16 + q * 4 + reg;
                if (row < rowEnd) {
                    const float v = acc[mi][ni][reg] + bv;
                    if constexpr (__is_same(OT, ushort))
                        C[row * 128 + col] = f2bf(v);
                    else
                        C[row * 128 + col] = v;
                }
            }
        }
    }
}

template <typename OT>
__global__ __launch_bounds__(256) void gemm_gcn(const ushort* __restrict__ A,
                                                const ushort* __restrict__ Wt,
                                                const float* __restrict__ bias,
                                                OT* __restrict__ C, int M) {
    __shared__ ushort wl[128 * 136];
    stage_wt(Wt, wl);
    __syncthreads();
    const long m0 = (long)blockIdx.x * 256;
    mfma_tile<ushort, OT>(A, wl, bias, C, m0, M);
    if (m0 + 128 < M)
        mfma_tile<ushort, OT>(A, wl, bias, C, m0 + 128, M);
}

// ---------------------------------------------------------------------------
// Ontology GEMM with fused attention-score epilogue.
// ---------------------------------------------------------------------------
struct GOnto {
    const ushort* Wt0; const ushort* Wt1; const ushort* Wt2;
    const float* s0; const float* s1; const float* s2;
    const float* d0; const float* d1; const float* d2;
    int bs1, bs2;
    int r1, r2, r3;
};

template <typename AT>
__global__ __launch_bounds__(256) void gemm_onto(const AT* x0, const AT* x1,
                                                 const AT* x2, GOnto g,
                                                 ushort* __restrict__ H,
                                                 float* __restrict__ as_o,
                                                 float* __restrict__ ad_o) {
    __shared__ ushort wl[128 * 136];
    const int b = blockIdx.x;
    const int gid = (b >= g.bs1) + (b >= g.bs2);
    const ushort* Wt = (gid == 0) ? g.Wt0 : (gid == 1) ? g.Wt1 : g.Wt2;
    const float* avs = (gid == 0) ? g.s0 : (gid == 1) ? g.s1 : g.s2;
    const float* avd = (gid == 0) ? g.d0 : (gid == 1) ? g.d1 : g.d2;
    const AT* Ag = (gid == 0) ? x0 : (gid == 1) ? x1 : x2;
    const int bloc = b - ((gid == 0) ? 0 : (gid == 1) ? g.bs1 : g.bs2);
    const long rb = (gid == 0) ? 0 : (gid == 1) ? g.r1 : g.r2;
    const long Mg = ((gid == 0) ? g.r1 : (gid == 1) ? g.r2 : g.r3) - rb;
    stage_wt(Wt, wl);
    __syncthreads();

    const int tid = threadIdx.x;
    const int wave = tid >> 6, lane = tid & 63;
    const int r = lane & 15, q = lane >> 4;
    const long m0 = (long)bloc * 128 + wave * 32;

    f32x4 acc[2][8];
#pragma unroll
    for (int mi = 0; mi < 2; ++mi)
#pragma unroll
        for (int ni = 0; ni < 8; ++ni) acc[mi][ni] = (f32x4)0.f;

#pragma unroll
    for (int t = 0; t < 4; ++t) {
        const int koff = t * 32 + q * 8;
        short8 bfr[8];
#pragma unroll
        for (int ni = 0; ni < 8; ++ni) {
            const uint4 raw = *(const uint4*)(&wl[(ni * 16 + r) * 136 + koff]);
            bfr[ni] = __builtin_bit_cast(short8, raw);
        }
#pragma unroll
        for (int mi = 0; mi < 2; ++mi) {
            long row = m0 + mi * 16 + r;
            if (row >= Mg) row = Mg - 1;
            short8 af;
            load_afrag<AT>(Ag, row, koff, af);
#pragma unroll
            for (int ni = 0; ni < 8; ++ni)
                acc[mi][ni] = __builtin_amdgcn_mfma_f32_16x16x32_bf16(
                    af, bfr[ni], acc[mi][ni], 0, 0, 0);
        }
    }

    ushort* Hg = H + rb * 128;
#pragma unroll
    for (int mi = 0; mi < 2; ++mi) {
#pragma unroll
        for (int ni = 0; ni < 8; ++ni) {
            const int col = ni * 16 + r;
#pragma unroll
            for (int reg = 0; reg < 4; ++reg) {
                const long row = m0 + mi * 16 + q * 4 + reg;
                if (row < Mg) Hg[row * 128 + col] = f2bf(acc[mi][ni][reg]);
            }
        }
    }

    float asv[8], adv[8];
#pragma unroll
    for (int ni = 0; ni < 8; ++ni) {
        asv[ni] = avs[ni * 16 + r];
        adv[ni] = avd[ni * 16 + r];
    }
#pragma unroll
    for (int mi = 0; mi < 2; ++mi) {
#pragma unroll
        for (int reg = 0; reg < 4; ++reg) {
            float ps = 0.f, pd = 0.f;
#pragma unroll
            for (int ni = 0; ni < 8; ++ni) {
                ps += acc[mi][ni][reg] * asv[ni];
                pd += acc[mi][ni][reg] * adv[ni];
            }
#pragma unroll
            for (int o = 1; o < 16; o <<= 1) {
                ps += __shfl_xor(ps, o);
                pd += __shfl_xor(pd, o);
            }
            const long row = m0 + mi * 16 + q * 4 + reg;
            if (r == 0 && row < Mg) {
                as_o[rb + row] = ps;
                ad_o[rb + row] = pd;
            }
        }
    }
}

// ---------------------------------------------------------------------------
// GAT aggregation: quarter-wave per node.
// ---------------------------------------------------------------------------
struct GatP {
    int r1, r2;
    int ob0, ob1, ob2;
    const float* b0; const float* b1; const float* b2;
};

__device__ __forceinline__ void acc8(float* acc, float w, const uint4 v) {
    acc[0] += w * bf2f(v.x & 0xffff);
    acc[1] += w * bf2f(v.x >> 16);
    acc[2] += w * bf2f(v.y & 0xffff);
    acc[3] += w * bf2f(v.y >> 16);
    acc[4] += w * bf2f(v.z & 0xffff);
    acc[5] += w * bf2f(v.z >> 16);
    acc[6] += w * bf2f(v.w & 0xffff);
    acc[7] += w * bf2f(v.w >> 16);
}

__global__ __launch_bounds__(256) void gat_all(const ushort* __restrict__ h,
                                               const float* __restrict__ as,
                                               const float* __restrict__ ad,
                                               const int* __restrict__ offs,
                                               const int* __restrict__ srcl,
                                               GatP p, ushort* __restrict__ out,
                                               int Mtot) {
    const int node = blockIdx.x * 16 + (threadIdx.x >> 4);
    const int ql = threadIdx.x & 15;
    if (node >= Mtot) return;
    const int gid = (node >= p.r1) + (node >= p.r2);
    const int rb = (gid == 0) ? 0 : (gid == 1) ? p.r1 : p.r2;
    const int ob = (gid == 0) ? p.ob0 : (gid == 1) ? p.ob1 : p.ob2;
    const float* bias = (gid == 0) ? p.b0 : (gid == 1) ? p.b1 : p.b2;
    const int local = node - rb;
    const int beg = offs[ob + local], end = offs[ob + local + 1];
    const float adv = ad[node];
    float m = -1e30f;
    for (int j = beg; j < end; ++j) {
        float e = as[rb + srcl[j]] + adv;
        e = (e > 0.f) ? e : 0.2f * e;
        m = fmaxf(m, e);
    }
    float denom = 0.f;
    float acc[8] = {0.f, 0.f, 0.f, 0.f, 0.f, 0.f, 0.f, 0.f};
    int j = beg;
    for (; j + 2 <= end; j += 2) {
        const int s0 = srcl[j], s1 = srcl[j + 1];
        float e0 = as[rb + s0] + adv; e0 = (e0 > 0.f) ? e0 : 0.2f * e0;
        float e1 = as[rb + s1] + adv; e1 = (e1 > 0.f) ? e1 : 0.2f * e1;
        const float w0 = __expf(e0 - m), w1 = __expf(e1 - m);
        const uint4 v0 = *(const uint4*)(h + (size_t)(rb + s0) * 128 + ql * 8);
        const uint4 v1 = *(const uint4*)(h + (size_t)(rb + s1) * 128 + ql * 8);
        denom += w0 + w1;
        acc8(acc, w0, v0);
        acc8(acc, w1, v1);
    }
    if (j < end) {
        const int s0 = srcl[j];
        float e0 = as[rb + s0] + adv; e0 = (e0 > 0.f) ? e0 : 0.2f * e0;
        const float w0 = __expf(e0 - m);
        const uint4 v0 = *(const uint4*)(h + (size_t)(rb + s0) * 128 + ql * 8);
        denom += w0;
        acc8(acc, w0, v0);
    }
    const float inv = 1.f / denom;
    const float4 bv0 = *(const float4*)(bias + ql * 8);
    const float4 bv1 = *(const float4*)(bias + ql * 8 + 4);
    uint4 o;
    o.x = (uint)f2bf(acc[0] * inv + bv0.x) | ((uint)f2bf(acc[1] * inv + bv0.y) << 16);
    o.y = (uint)f2bf(acc[2] * inv + bv0.z) | ((uint)f2bf(acc[3] * inv + bv0.w) << 16);
    o.z = (uint)f2bf(acc[4] * inv + bv1.x) | ((uint)f2bf(acc[5] * inv + bv1.y) << 16);
    o.w = (uint)f2bf(acc[6] * inv + bv1.z) | ((uint)f2bf(acc[7] * inv + bv1.w) << 16);
    *(uint4*)(out + (size_t)node * 128 + ql * 8) = o;
}

// ---------------------------------------------------------------------------
// Batched CSR build (8 lists; self-loops atomic-free in reserved last slot).
// Patient slots -> int4 record {src, gxi, nw_bits, 0}, written ONLY for dst
// nodes whose edge lists will actually be read (mk != 0).
// ---------------------------------------------------------------------------
struct CsrDesc {
    const int* esrc[8];
    const int* edst[8];
    int ebase[9];
    int nbase[9];
    int totE;
};

__global__ void csr_count_b(CsrDesc d, int* __restrict__ cnt, int* __restrict__ pos) {
    const int i = blockIdx.x * 256 + threadIdx.x;
    if (i >= d.totE) return;
    int li = 0;
#pragma unroll
    for (int k = 1; k < 8; ++k) li += (i >= d.ebase[k]);
    const int v = d.nbase[li] + d.edst[li][i - d.ebase[li]];
    pos[i] = atomicAdd(&cnt[v], 1);
}

__global__ void csr_fill_b(CsrDesc d, const int* __restrict__ offs,
                           const int* __restrict__ pos, const int* __restrict__ cnt,
                           int* __restrict__ srcl, int4* __restrict__ pedge,
                           const float* __restrict__ dinv,
                           const int* __restrict__ lx, const int* __restrict__ rx,
                           const int* __restrict__ mk,
                           int NP, int NV, int pB) {
    const int i = blockIdx.x * 256 + threadIdx.x;
    int v, s, li, idx;
    if (i < d.totE) {
        li = 0;
#pragma unroll
        for (int k = 1; k < 8; ++k) li += (i >= d.ebase[k]);
        const int j = i - d.ebase[li];
        v = d.nbase[li] + d.edst[li][j];
        s = d.esrc[li][j];
        idx = offs[v] + pos[i];
    } else if (i < d.totE + NV) {
        v = i - d.totE;
        li = 0;
#pragma unroll
        for (int k = 1; k < 8; ++k) li += (v >= d.nbase[k]);
        s = v - d.nbase[li];
        idx = offs[v] + cnt[v];
    } else return;
    if (li >= 6) {
        const int n2l = v - d.nbase[6];
        if (mk[n2l] == 0) return;   // edge list never read
        const int sg = (li - 6) * NP + s;
        int4 rec;
        rec.x = sg;
        rec.y = (li == 7 ? rx : lx)[s];
        rec.z = __float_as_int(dinv[n2l] * dinv[sg]);
        rec.w = 0;
        pedge[idx - pB] = rec;
    } else {
        srcl[idx] = s;
    }
}

// First node of each graph (sorted batch); sets fin bit (1) in mk.
__global__ void first_node(const int* __restrict__ bL, const int* __restrict__ bR,
                           int NP, int* __restrict__ gfL, int* __restrict__ gfR,
                           int* __restrict__ mk) {
    const int i = blockIdx.x * 256 + threadIdx.x;
    if (i >= 2 * NP) return;
    const int side = i >= NP;
    const int ii = i - (side ? NP : 0);
    const int* b = side ? bR : bL;
    int* gf = side ? gfR : gfL;
    const int cur = b[ii];
    const int prev = (ii == 0) ? -1 : b[ii - 1];
    if (cur > prev) {
        for (int g = prev + 1; g <= cur; ++g) gf[g] = ii;
        mk[i] = 1;
    }
}

// Backward reachability marking (non-returning atomicOr only — G12).
__global__ void mark_k(const int* __restrict__ lEg, const int* __restrict__ rEg,
                       int EP, int NP, int* __restrict__ mk, int testBit, int setBit) {
    const int i = blockIdx.x * 256 + threadIdx.x;
    int src, dst;
    if (i < 2 * EP) {
        const int side = i >= EP;
        const int e = i - side * EP;
        const int* eg = side ? rEg : lEg;
        src = side * NP + eg[e];
        dst = side * NP + eg[EP + e];
    } else if (i < 2 * EP + 2 * NP) {
        src = dst = i - 2 * EP;   // self-loop
    } else return;
    if (mk[dst] & testBit) atomicOr(&mk[src], setBit);
}

// ---------------------------------------------------------------------------
// 3-phase exclusive scan over (cnt[v]+1); emits dinv for the patient range.
// ---------------------------------------------------------------------------
__global__ __launch_bounds__(1024) void scan_tile(const int* __restrict__ in,
                                                  int* __restrict__ out,
                                                  int* __restrict__ bsum, int n,
                                                  int pn0, int pcnt,
                                                  float* __restrict__ dinv) {
    __shared__ int buf[1024];
    const int tid = threadIdx.x;
    const int i = blockIdx.x * 1024 + tid;
    const int v = (i < n) ? (in[i] + 1) : 0;
    if (i >= pn0 && i < pn0 + pcnt)
        dinv[i - pn0] = rsqrtf(fmaxf((float)v, 1e-12f));
    buf[tid] = v;
    __syncthreads();
    int x = v;
    for (int o = 1; o < 1024; o <<= 1) {
        const int t = (tid >= o) ? buf[tid - o] : 0;
        __syncthreads();
        x += t;
        buf[tid] = x;
        __syncthreads();
    }
    if (i < n) out[i] = x - v;
    if (tid == 1023) bsum[blockIdx.x] = x;
}

__global__ __launch_bounds__(1024) void scan_single(int* __restrict__ bsum, int nb) {
    __shared__ int buf[1024];
    const int tid = threadIdx.x;
    const int v = (tid < nb) ? bsum[tid] : 0;
    buf[tid] = v;
    __syncthreads();
    int x = v;
    for (int o = 1; o < 1024; o <<= 1) {
        const int t = (tid >= o) ? buf[tid - o] : 0;
        __syncthreads();
        x += t;
        buf[tid] = x;
        __syncthreads();
    }
    if (tid < nb) bsum[tid] = x - v;
    if (tid == 1023) bsum[nb] = x;
}

__global__ void scan_add(int* __restrict__ out, const int* __restrict__ bsum,
                         int n, int nb) {
    const int i = blockIdx.x * 256 + threadIdx.x;
    if (i < n) out[i] += bsum[i >> 10];
    else if (i == n) out[i] = bsum[nb];
}

// ---------------------------------------------------------------------------
// allemb (bf16): row 0 = spec (fp32 src), then 3 ontology maps from bf16 oE.
// ---------------------------------------------------------------------------
struct EmbD {
    const float* spec; const ushort* oE;
    const int* m0; const int* m1; const int* m2;
    int lb2, lb3;
    int r1, r2;
    long ALLr;
};

__global__ void build_emb(EmbD d, ushort* __restrict__ out) {
    const long t = (long)blockIdx.x * 256 + threadIdx.x;
    if (t >= d.ALLr * 16) return;
    const int row = (int)(t >> 4), c = (int)(t & 15);
    uint4 o;
    if (row == 0) {
        const float4 f0 = ((const float4*)d.spec)[c * 2];
        const float4 f1 = ((const float4*)d.spec)[c * 2 + 1];
        o.x = (uint)f2bf(f0.x) | ((uint)f2bf(f0.y) << 16);
        o.y = (uint)f2bf(f0.z) | ((uint)f2bf(f0.w) << 16);
        o.z = (uint)f2bf(f1.x) | ((uint)f2bf(f1.y) << 16);
        o.w = (uint)f2bf(f1.z) | ((uint)f2bf(f1.w) << 16);
    } else {
        const int seg = (row >= d.lb2) + (row >= d.lb3);
        const int local = row - ((seg == 0) ? 1 : (seg == 1) ? d.lb2 : d.lb3);
        const int* mp = (seg == 0) ? d.m0 : (seg == 1) ? d.m1 : d.m2;
        const int rb = (seg == 0) ? 0 : (seg == 1) ? d.r1 : d.r2;
        o = ((const uint4*)(d.oE + (size_t)(rb + mp[local]) * 128))[c];
    }
    ((uint4*)out)[(size_t)row * 16 + c] = o;
}

// ---------------------------------------------------------------------------
// GCN aggregations: quarter-wave per node, early exit on mk bit.
// Edge record = int4 {src, gxi, nw, 0}.
// ---------------------------------------------------------------------------
__global__ __launch_bounds__(256) void gcn_agg1(const ushort* __restrict__ A3,
                                                const int4* __restrict__ pedge,
                                                const int* __restrict__ offs6,
                                                const float* __restrict__ c1,
                                                ushort* __restrict__ t1,
                                                const int* __restrict__ mk,
                                                int NP2, int pB) {
    const int n2 = blockIdx.x * 16 + (threadIdx.x >> 4);
    const int ql = threadIdx.x & 15;
    if (n2 >= NP2) return;
    if ((mk[n2] & 4) == 0) return;   // t1 row never read
    const int beg = offs6[n2] - pB, end = offs6[n2 + 1] - pB;
    float acc[8] = {0.f, 0.f, 0.f, 0.f, 0.f, 0.f, 0.f, 0.f};
    int j = beg;
    for (; j + 2 <= end; j += 2) {
        const int4 r0 = pedge[j], r1 = pedge[j + 1];
        const float w0 = __int_as_float(r0.z), w1 = __int_as_float(r1.z);
        const uint4 v0 = *(const uint4*)(A3 + (size_t)r0.y * 128 + ql * 8);
        const uint4 v1 = *(const uint4*)(A3 + (size_t)r1.y * 128 + ql * 8);
        acc8(acc, w0, v0);
        acc8(acc, w1, v1);
    }
    if (j < end) {
        const int4 r0 = pedge[j];
        const uint4 v0 = *(const uint4*)(A3 + (size_t)r0.y * 128 + ql * 8);
        acc8(acc, __int_as_float(r0.z), v0);
    }
    const float4 bv0 = *(const float4*)(c1 + ql * 8);
    const float4 bv1 = *(const float4*)(c1 + ql * 8 + 4);
    uint4 o;
    o.x = (uint)f2bf(acc[0] + bv0.x) | ((uint)f2bf(acc[1] + bv0.y) << 16);
    o.y = (uint)f2bf(acc[2] + bv0.z) | ((uint)f2bf(acc[3] + bv0.w) << 16);
    o.z = (uint)f2bf(acc[4] + bv1.x) | ((uint)f2bf(acc[5] + bv1.y) << 16);
    o.w = (uint)f2bf(acc[6] + bv1.z) | ((uint)f2bf(acc[7] + bv1.w) << 16);
    *(uint4*)(t1 + (size_t)n2 * 128 + ql * 8) = o;
}

__device__ __forceinline__ void gcn_q_acc(const ushort* __restrict__ x,
                                          const int4* __restrict__ pedge,
                                          int beg, int end, int ql, float* acc) {
    int j = beg;
    for (; j + 2 <= end; j += 2) {
        const int4 r0 = pedge[j], r1 = pedge[j + 1];
        const float w0 = __int_as_float(r0.z), w1 = __int_as_float(r1.z);
        const uint4 v0 = *(const uint4*)(x + (size_t)r0.x * 128 + ql * 8);
        const uint4 v1 = *(const uint4*)(x + (size_t)r1.x * 128 + ql * 8);
        acc8(acc, w0, v0);
        acc8(acc, w1, v1);
    }
    if (j < end) {
        const int4 r0 = pedge[j];
        const uint4 v0 = *(const uint4*)(x + (size_t)r0.x * 128 + ql * 8);
        acc8(acc, __int_as_float(r0.z), v0);
    }
}

__global__ __launch_bounds__(256) void gcn_agg2(const ushort* __restrict__ t1,
                                                const int4* __restrict__ pedge,
                                                const int* __restrict__ offs6,
                                                const float* __restrict__ c2,
                                                ushort* __restrict__ t2,
                                                const int* __restrict__ mk,
                                                int NP2, int pB) {
    const int n2 = blockIdx.x * 16 + (threadIdx.x >> 4);
    const int ql = threadIdx.x & 15;
    if (n2 >= NP2) return;
    if ((mk[n2] & 2) == 0) return;   // t2 row never read
    const int beg = offs6[n2] - pB, end = offs6[n2 + 1] - pB;
    float acc[8] = {0.f, 0.f, 0.f, 0.f, 0.f, 0.f, 0.f, 0.f};
    gcn_q_acc(t1, pedge, beg, end, ql, acc);
    const float4 bv0 = *(const float4*)(c2 + ql * 8);
    const float4 bv1 = *(const float4*)(c2 + ql * 8 + 4);
    uint4 o;
    o.x = (uint)f2bf(acc[0] + bv0.x) | ((uint)f2bf(acc[1] + bv0.y) << 16);
    o.y = (uint)f2bf(acc[2] + bv0.z) | ((uint)f2bf(acc[3] + bv0.w) << 16);
    o.z = (uint)f2bf(acc[4] + bv1.x) | ((uint)f2bf(acc[5] + bv1.y) << 16);
    o.w = (uint)f2bf(acc[6] + bv1.z) | ((uint)f2bf(acc[7] + bv1.w) << 16);
    *(uint4*)(t2 + (size_t)n2 * 128 + ql * 8) = o;
}

// Fused final layer + cosine: 32 lanes per graph (16 left, 16 right);
// shfl_xor(16) exchanges sides for the dot product. Writes out[g] directly.
__global__ __launch_bounds__(256) void final_cos(const ushort* __restrict__ t2,
                                                 const int4* __restrict__ pedge,
                                                 const int* __restrict__ offs6,
                                                 const int* __restrict__ gfL,
                                                 const int* __restrict__ gfR,
                                                 const float* __restrict__ b3,
                                                 float* __restrict__ out,
                                                 int B, int NP, int pB) {
    const int g = blockIdx.x * 8 + (threadIdx.x >> 5);
    const int l32 = threadIdx.x & 31;
    const int side = l32 >> 4;
    const int ql = l32 & 15;
    if (g >= B) return;
    const int n2 = (side ? NP : 0) + (side ? gfR : gfL)[g];
    const int beg = offs6[n2] - pB, end = offs6[n2 + 1] - pB;
    float acc[8] = {0.f, 0.f, 0.f, 0.f, 0.f, 0.f, 0.f, 0.f};
    gcn_q_acc(t2, pedge, beg, end, ql, acc);
    const float4 bv0 = *(const float4*)(b3 + ql * 8);
    const float4 bv1 = *(const float4*)(b3 + ql * 8 + 4);
    float v[8];
    v[0] = acc[0] + bv0.x; v[1] = acc[1] + bv0.y;
    v[2] = acc[2] + bv0.z; v[3] = acc[3] + bv0.w;
    v[4] = acc[4] + bv1.x; v[5] = acc[5] + bv1.y;
    v[6] = acc[6] + bv1.z; v[7] = acc[7] + bv1.w;
    float num = 0.f, nself = 0.f, nother = 0.f;
#pragma unroll
    for (int j = 0; j < 8; ++j) {
        const float o = __shfl_xor(v[j], 16);
        num += v[j] * o;
        nself += v[j] * v[j];
        nother += o * o;
    }
#pragma unroll
    for (int o1 = 1; o1 < 16; o1 <<= 1) {
        num += __shfl_xor(num, o1);
        nself += __shfl_xor(nself, o1);
        nother += __shfl_xor(nother, o1);
    }
    if (l32 == 0)
        out[g] = num / (fmaxf(sqrtf(nself), 1e-6f) * fmaxf(sqrtf(nother), 1e-6f));
}

// ---------------------------------------------------------------------------
extern "C" void kernel_launch(void* const* d_in, const int* in_sizes, int n_in,
                              void* d_out, int out_size, void* d_ws, size_t ws_size,
                              hipStream_t stream) {
    (void)n_in; (void)ws_size;
    // setup_inputs() dict order
    const float* spec = (const float*)d_in[0];
    const float* tabs[3] = {(const float*)d_in[1], (const float*)d_in[2], (const float*)d_in[3]};
    const float* ontW[3] = {(const float*)d_in[4], (const float*)d_in[8], (const float*)d_in[12]};
    const float* ontAs[3] = {(const float*)d_in[5], (const float*)d_in[9], (const float*)d_in[13]};
    const float* ontAd[3] = {(const float*)d_in[6], (const float*)d_in[10], (const float*)d_in[14]};
    const float* ontB[3] = {(const float*)d_in[7], (const float*)d_in[11], (const float*)d_in[15]};
    const float* gcnW[3] = {(const float*)d_in[16], (const float*)d_in[18], (const float*)d_in[20]};
    const float* gcnB[3] = {(const float*)d_in[17], (const float*)d_in[19], (const float*)d_in[21]};
    const int* e1s[3] = {(const int*)d_in[22], (const int*)d_in[24], (const int*)d_in[26]};
    const int* e2s[3] = {(const int*)d_in[23], (const int*)d_in[25], (const int*)d_in[27]};
    const int* maps[3] = {(const int*)d_in[28], (const int*)d_in[29], (const int*)d_in[30]};
    const int* left_x = (const int*)d_in[31];
    const int* right_x = (const int*)d_in[32];
    const int* left_eg = (const int*)d_in[33];
    const int* right_eg = (const int*)d_in[34];
    const int* left_batch = (const int*)d_in[35];
    const int* right_batch = (const int*)d_in[36];

    int Ms[3] = {in_sizes[1] / HID, in_sizes[2] / HID, in_sizes[3] / HID};
    int E1s[3] = {in_sizes[22] / 2, in_sizes[24] / 2, in_sizes[26] / 2};
    int E2s[3] = {in_sizes[23] / 2, in_sizes[25] / 2, in_sizes[27] / 2};
    int Ls[3] = {in_sizes[28], in_sizes[29], in_sizes[30]};
    const int NP = in_sizes[31];
    const int EP = in_sizes[33] / 2;
    const int B = out_size;
    const long ALL = 1 + (long)Ls[0] + Ls[1] + Ls[2];
    const int Mtot = Ms[0] + Ms[1] + Ms[2];
    const int r1 = Ms[0], r2 = Ms[0] + Ms[1];

    // ---- batched CSR descriptor (8 lists; self-loops implicit) ----
    CsrDesc dsc;
    int eCnt[8], nCnt[8];
    for (int i = 0; i < 3; ++i) {
        dsc.esrc[2 * i] = e1s[i];     dsc.edst[2 * i] = e1s[i] + E1s[i];
        dsc.esrc[2 * i + 1] = e2s[i]; dsc.edst[2 * i + 1] = e2s[i] + E2s[i];
        eCnt[2 * i] = E1s[i]; eCnt[2 * i + 1] = E2s[i];
        nCnt[2 * i] = Ms[i];  nCnt[2 * i + 1] = Ms[i];
    }
    dsc.esrc[6] = left_eg;  dsc.edst[6] = left_eg + EP;  eCnt[6] = EP; nCnt[6] = NP;
    dsc.esrc[7] = right_eg; dsc.edst[7] = right_eg + EP; eCnt[7] = EP; nCnt[7] = NP;
    dsc.ebase[0] = 0;
    int nb_acc = 0;
    for (int i = 0; i < 8; ++i) {
        dsc.ebase[i + 1] = dsc.ebase[i] + eCnt[i];
        dsc.nbase[i] = nb_acc;
        nb_acc += nCnt[i];
    }
    const int NV = nb_acc;
    dsc.nbase[8] = NV;
    dsc.totE = dsc.ebase[8];
    const int totEntries = dsc.totE + NV;
    const int pB = dsc.ebase[6] + dsc.nbase[6];
    const int pEntries = totEntries - pB;

    // ---- workspace layout ----
    char* ws = (char*)d_ws;
    size_t off = 0;
    auto alloc = [&](size_t bytes) -> void* {
        off = (off + 255) & ~(size_t)255;
        void* p = ws + off;
        off += bytes;
        return p;
    };
    ushort* wt4 = (ushort*)alloc((size_t)4 * 16384 * 2);   // 3 ont Wt + WpT
    float* W23b = (float*)alloc((size_t)129 * 128 * 4);
    float* Pout = (float*)alloc((size_t)130 * 128 * 4);
    ushort* allemb = (ushort*)alloc((size_t)ALL * HID * 2);
    ushort* A3 = (ushort*)alloc((size_t)ALL * HID * 2);
    int* cnt = (int*)alloc((size_t)NV * 4);
    int* offs = (int*)alloc((size_t)(NV + 1) * 4);
    int* pos = (int*)alloc((size_t)dsc.totE * 4);
    int* srcl = (int*)alloc((size_t)pB * 4);
    int4* pedge = (int4*)alloc((size_t)pEntries * 16);
    int* bsum = (int*)alloc(1025 * 4);
    float* dinv = (float*)alloc((size_t)2 * NP * 4);
    float* as = (float*)alloc((size_t)Mtot * 4);
    float* ad = (float*)alloc((size_t)Mtot * 4);
    int* gfL = (int*)alloc((size_t)(B + 1) * 4);
    int* gfR = (int*)alloc((size_t)(B + 1) * 4);
    int* mk = (int*)alloc((size_t)2 * NP * 4);
    ushort* t1 = (ushort*)alloc((size_t)2 * NP * HID * 2);
    // big region: ontology hbuf/obuf first, then t2
    ushort* big = (ushort*)alloc((size_t)2 * NP * HID * 2);
    ushort* hbuf = big;                              // [Mtot x 128] bf16
    ushort* obuf = big + (size_t)Mtot * HID;         // [Mtot x 128] bf16
    ushort* t2 = big;                                // [2NP x 128] bf16 (later)

    // ---- weight folding (2 launches) ----
    fold1<<<cdiv_i(129 * 128, 256), 256, 0, stream>>>(gcnW[1], gcnB[1], gcnW[2], W23b);
    fold2<<<cdiv_i(130 * 128, 256), 256, 0, stream>>>(gcnW[0], gcnB[0], W23b, Pout);
    const float* c1 = Pout + 128 * 128;
    const float* c2 = Pout + 129 * 128;

    // ---- weight transpose (bf16): 3 ont + folded Wp ----
    W4 w4;
    w4.w[0] = ontW[0]; w4.w[1] = ontW[1]; w4.w[2] = ontW[2]; w4.w[3] = Pout;
    wtrans_k<<<cdiv_i(4 * 16384, 256), 256, 0, stream>>>(w4, wt4);
    const ushort* wtOnt[3] = {wt4, wt4 + 16384, wt4 + 2 * 16384};
    const ushort* WpT = wt4 + 3 * 16384;

    // ---- backward reachability marks (raw edges; non-returning atomics) ----
    hipMemsetAsync(mk, 0, (size_t)2 * NP * 4, stream);
    first_node<<<cdiv_i(2 * NP, 256), 256, 0, stream>>>(left_batch, right_batch,
                                                        NP, gfL, gfR, mk);
    mark_k<<<cdiv_i(2 * EP + 2 * NP, 256), 256, 0, stream>>>(
        left_eg, right_eg, EP, NP, mk, 1, 2);
    mark_k<<<cdiv_i(2 * EP + 2 * NP, 256), 256, 0, stream>>>(
        left_eg, right_eg, EP, NP, mk, 2, 4);

    // ---- CSR build ----
    hipMemsetAsync(cnt, 0, (size_t)NV * 4, stream);
    csr_count_b<<<cdiv_i(dsc.totE, 256), 256, 0, stream>>>(dsc, cnt, pos);
    {
        const int nb = cdiv_i(NV, 1024);
        scan_tile<<<nb, 1024, 0, stream>>>(cnt, offs, bsum, NV, dsc.nbase[6],
                                           2 * NP, dinv);
        scan_single<<<1, 1024, 0, stream>>>(bsum, nb);
        scan_add<<<cdiv_i(NV + 1, 256), 256, 0, stream>>>(offs, bsum, NV, nb);
    }
    csr_fill_b<<<cdiv_i(totEntries, 256), 256, 0, stream>>>(dsc, offs, pos, cnt,
                                                            srcl, pedge, dinv,
                                                            left_x, right_x, mk,
                                                            NP, NV, pB);

    // ---- ontology: 2 GAT layers (transform-first, fused scores) ----
    GOnto go;
    go.Wt0 = wtOnt[0]; go.Wt1 = wtOnt[1]; go.Wt2 = wtOnt[2];
    go.s0 = ontAs[0]; go.s1 = ontAs[1]; go.s2 = ontAs[2];
    go.d0 = ontAd[0]; go.d1 = ontAd[1]; go.d2 = ontAd[2];
    go.bs1 = cdiv_i(Ms[0], 128);
    go.bs2 = go.bs1 + cdiv_i(Ms[1], 128);
    const int totBlk = go.bs2 + cdiv_i(Ms[2], 128);
    go.r1 = r1; go.r2 = r2; go.r3 = Mtot;

    for (int layer = 0; layer < 2; ++layer) {
        const GatP gp{r1, r2,
                      dsc.nbase[0 + layer], dsc.nbase[2 + layer], dsc.nbase[4 + layer],
                      ontB[0], ontB[1], ontB[2]};
        if (layer == 0)
            gemm_onto<float><<<totBlk, 256, 0, stream>>>(tabs[0], tabs[1], tabs[2],
                                                         go, hbuf, as, ad);
        else
            gemm_onto<ushort><<<totBlk, 256, 0, stream>>>(
                obuf, obuf + (size_t)r1 * HID, obuf + (size_t)r2 * HID,
                go, hbuf, as, ad);
        gat_all<<<cdiv_i(Mtot, 16), 256, 0, stream>>>(hbuf, as, ad, offs, srcl, gp,
                                                      obuf, Mtot);
    }

    EmbD ed;
    ed.spec = spec; ed.oE = obuf;
    ed.m0 = maps[0]; ed.m1 = maps[1]; ed.m2 = maps[2];
    ed.lb2 = 1 + Ls[0]; ed.lb3 = 1 + Ls[0] + Ls[1];
    ed.r1 = r1; ed.r2 = r2; ed.ALLr = ALL;
    build_emb<<<cdiv_i(ALL * 16, 256), 256, 0, stream>>>(ed, allemb);

    // ---- patient: folded GCN = 1 small GEMM + sparsified aggregations ----
    const int* offs6 = offs + dsc.nbase[6];
    gemm_gcn<ushort><<<cdiv_i(ALL, 256), 256, 0, stream>>>(
        allemb, WpT, nullptr, A3, (int)ALL);
    gcn_agg1<<<cdiv_i(2 * NP, 16), 256, 0, stream>>>(A3, pedge, offs6, c1, t1,
                                                     mk, 2 * NP, pB);
    gcn_agg2<<<cdiv_i(2 * NP, 16), 256, 0, stream>>>(t1, pedge, offs6, c2, t2,
                                                     mk, 2 * NP, pB);
    final_cos<<<cdiv_i(B, 8), 256, 0, stream>>>(t2, pedge, offs6, gfL, gfR,
                                                gcnB[2], (float*)d_out, B, NP, pB);
}